// Round 6
// baseline (272.716 us; speedup 1.0000x reference)
//
#include <hip/hip_runtime.h>
#include <hip/hip_bf16.h>

#define DEV static __device__ __forceinline__

typedef unsigned short ushort;
typedef __attribute__((ext_vector_type(8))) short short8;
typedef __attribute__((ext_vector_type(8))) ushort ushort8;
typedef __attribute__((ext_vector_type(4))) ushort ushortx4;
typedef __attribute__((ext_vector_type(4))) float accv;

DEV ushort f2bf(float f) {
    __hip_bfloat16 h = __float2bfloat16(f);   // RNE
    return reinterpret_cast<ushort&>(h);
}

// ---------------------------------------------------------------------------
// Static device workspace
// ---------------------------------------------------------------------------
__device__ float    g_sred[5 * 128 * 32];             // [l][co][32]: 0=sum 1=sumsq 2=maskcnt
__device__ float    g_part1[128 * 96];                // conv1 bucketed stats [bkt][co*3+s]
__device__ float    g_part5[64 * 192];                // conv5 bucketed stats [bkt][co*3+s]
__device__ float    g_y1[2097152];                    // (2,32,32^3) fp32 NCV
__device__ __align__(16) ushort g_y1b[2097152];       // (2,32^3,32) bf16 VC
__device__ float    g_m1[65536];
__device__ float    g_y2[524288];
__device__ __align__(16) ushort g_y2b[524288];        // (2,16^3,64) bf16 VC
__device__ float    g_m2[8192];
__device__ float    g_y3[131072];
__device__ __align__(16) ushort g_y3b[131072];        // (2,8^3,128) bf16 VC
__device__ float    g_m3[1024];
__device__ float    g_t1[1048576];
__device__ __align__(16) ushort g_t1b[1048576];       // (2,16^3,128) bf16 VC
__device__ float    g_mt1[8192];
__device__ float    g_mt2[65536];
__device__ float    g_t2[4194304];                    // conv5 raw out (fp32 NCV)
__device__ __align__(16) ushort g_x0b[2097152];       // (2,64^3,4) bf16 VC masked feat
// split-K partial buffers
__device__ float    g_p2[4194304];                    // 4  x 524288 used
__device__ float    g_p3[4194304];                    // 32 x 131072
__device__ float    g_p4[8388608];                    // 4  x 1048576 used
// K-major weights
__device__ __align__(16) ushort g_wb1[8192];          // [32co][256k] bf16, k=tap*4+ci
__device__ __align__(16) ushort g_wb2[131072];
__device__ __align__(16) ushort g_wb3[524288];
__device__ __align__(16) ushort g_wb4[1048576];
__device__ __align__(16) ushort g_wb5[524288];
__device__ float    g_fwt[2048];                      // [k=64][co=32] fp32

// ---------------------------------------------------------------------------
// prep_all (verified round-11/12)
// ---------------------------------------------------------------------------
__global__ __launch_bounds__(256)
void prep_all_kernel(const float* __restrict__ w1, const float* __restrict__ fw,
                     const float* __restrict__ w2, const float* __restrict__ w3,
                     const float* __restrict__ tw1, const float* __restrict__ tw2,
                     const float* __restrict__ feat, const float* __restrict__ mask) {
    int blk = blockIdx.x, tid = threadIdx.x;
    if (blk < 96) {
        int idx = blk * 256 + tid;
        if (idx < 20480) g_sred[idx] = 0.f;
        if (idx < 12288) g_part1[idx] = 0.f;
        if (idx < 12288) g_part5[idx] = 0.f;
        if (idx < 8192) {
            int co = idx >> 8, r = idx & 255;
            int tap = r >> 2, ci = r & 3;
            g_wb1[idx] = f2bf(w1[co * 256 + ci * 64 + tap]);
        }
        if (idx < 2048) { int co = idx >> 6, kg = idx & 63; g_fwt[kg * 32 + co] = fw[idx]; }
    } else if (blk < 608) {
        int idx = (blk - 96) * 256 + tid;
        int co = idx / 2048, r = idx % 2048;
        int ci = r >> 6, tap = r & 63;
        g_wb2[(size_t)co * 2048 + tap * 32 + ci] = f2bf(w2[idx]);
    } else if (blk < 2656) {
        int idx = (blk - 608) * 256 + tid;
        int co = idx / 4096, r = idx % 4096;
        int ci = r >> 6, tap = r & 63;
        g_wb3[(size_t)co * 4096 + tap * 64 + ci] = f2bf(w3[idx]);
    } else if (blk < 6752) {
        int idx = (blk - 2656) * 256 + tid;
        int co = idx / 8192, r = idx % 8192;
        int ci = r >> 6, t64 = r & 63;
        int kd = t64 >> 4, kh = (t64 >> 2) & 3, kw = t64 & 3;
        int pd = (3 - kd) & 1, td = (3 - kd) >> 1;
        int ph = (3 - kh) & 1, th = (3 - kh) >> 1;
        int pw = (3 - kw) & 1, tw = (3 - kw) >> 1;
        int parity = pd * 4 + ph * 2 + pw, t = td * 4 + th * 2 + tw;
        g_wb4[(((size_t)parity * 128 + co) * 8 + t) * 128 + ci] = f2bf(tw1[idx]);
    } else if (blk < 8800) {
        int idx = (blk - 6752) * 256 + tid;
        int co = idx / 8192, r = idx % 8192;
        int ci = r >> 6, t64 = r & 63;
        int kd = t64 >> 4, kh = (t64 >> 2) & 3, kw = t64 & 3;
        int pd = (3 - kd) & 1, td = (3 - kd) >> 1;
        int ph = (3 - kh) & 1, th = (3 - kh) >> 1;
        int pw = (3 - kw) & 1, tw = (3 - kw) >> 1;
        int parity = pd * 4 + ph * 2 + pw, t = td * 4 + th * 2 + tw;
        g_wb5[(((size_t)parity * 64 + co) * 8 + t) * 128 + ci] = f2bf(tw2[idx]);
    } else if (blk < 10848) {
        int idx = (blk - 8800) * 256 + tid;
        int b = idx >> 18, v = idx & 0x3FFFF;
        float mv = mask[idx] > 0.5f ? 1.f : 0.f;
        ushort pk[4];
#pragma unroll
        for (int c = 0; c < 4; c++) pk[c] = f2bf(feat[((b * 4 + c) << 18) + v] * mv);
        *(ushortx4*)&g_x0b[(size_t)idx * 4] = (ushortx4){pk[0], pk[1], pk[2], pk[3]};
    } else {
        int idx = (blk - 10848) * 256 + tid;            // mask1: 65536
        int b = idx >> 15, v = idx & 0x7FFF;
        int od = v >> 10, rem = v & 1023;
        int oh = rem >> 5, ow = rem & 31;
        const float* mp = mask + ((size_t)b << 18);
        float acc = 0.f;
        for (int kd = 0; kd < 4; kd++) {
            int id = 2 * od - 1 + kd;
            if ((unsigned)id >= 64u) continue;
            for (int kh = 0; kh < 4; kh++) {
                int ih = 2 * oh - 1 + kh;
                if ((unsigned)ih >= 64u) continue;
                const float* row = mp + ((size_t)id * 64 + ih) * 64;
                for (int kw = 0; kw < 4; kw++) {
                    int iw = 2 * ow - 1 + kw;
                    if ((unsigned)iw < 64u && row[iw] > 0.5f) acc += 1.f;
                }
            }
        }
        g_m1[idx] = acc > 0.f ? 1.f : 0.f;
    }
}

// ---------------------------------------------------------------------------
// mask dilation bodies with explicit block index (fused into bn kernels)
// ---------------------------------------------------------------------------
DEV void mask_down_blk(const float* mprev, float* mout, int logDin, int logDo, int blk) {
    int Din = 1 << logDin, Do = 1 << logDo;
    int idx = blk * 256 + threadIdx.x;
    int b = idx >> (3 * logDo), v = idx & ((1 << (3 * logDo)) - 1);
    int od = v >> (2 * logDo), rem = v & ((1 << (2 * logDo)) - 1);
    int oh = rem >> logDo, ow = rem & (Do - 1);
    const float* mp = mprev + ((size_t)b << (3 * logDin));
    float acc = 0.f;
    for (int kd = 0; kd < 4; kd++) {
        int id = 2 * od - 1 + kd;
        if ((unsigned)id >= (unsigned)Din) continue;
        for (int kh = 0; kh < 4; kh++) {
            int ih = 2 * oh - 1 + kh;
            if ((unsigned)ih >= (unsigned)Din) continue;
            const float* row = mp + ((size_t)id * Din + ih) * Din;
            for (int kw = 0; kw < 4; kw++) {
                int iw = 2 * ow - 1 + kw;
                if ((unsigned)iw < (unsigned)Din) acc += row[iw];
            }
        }
    }
    mout[idx] = acc > 0.f ? 1.f : 0.f;
}

DEV void mask_up_blk(const float* mprev, float* mout, int logDin, int logDo, int blk) {
    int Din = 1 << logDin, Do = 1 << logDo;
    int idx = blk * 256 + threadIdx.x;
    int b = idx >> (3 * logDo), v = idx & ((1 << (3 * logDo)) - 1);
    int od = v >> (2 * logDo), rem = v & ((1 << (2 * logDo)) - 1);
    int oh = rem >> logDo, ow = rem & (Do - 1);
    const float* mp = mprev + ((size_t)b << (3 * logDin));
    float acc = 0.f;
    for (int kd = 0; kd < 4; kd++) {
        int u = od + kd - 2; if (u < 0 || (u & 1)) continue;
        int id = u >> 1; if (id >= Din) continue;
        for (int kh = 0; kh < 4; kh++) {
            int uh = oh + kh - 2; if (uh < 0 || (uh & 1)) continue;
            int ih = uh >> 1; if (ih >= Din) continue;
            const float* row = mp + ((size_t)id * Din + ih) * Din;
            for (int kw = 0; kw < 4; kw++) {
                int uw = ow + kw - 2; if (uw < 0 || (uw & 1)) continue;
                int iw = uw >> 1; if (iw >= Din) continue;
                acc += row[iw];
            }
        }
    }
    mout[idx] = acc > 0.f ? 1.f : 0.f;
}

// ---------------------------------------------------------------------------
// bf16 MFMA implicit-GEMM, register-prefetch pipelined, hoisted B-decode.
// A staged cooperatively through LDS (verified round-0 structure).
// KT = K-tile per barrier pair. Per-slot tap decode in gatherB makes KT=64
// legal for any CIN >= 8 (each ushort8 stays within one spatial tap).
// Optional fused BN-stats epilogue (STATS): bucketed global atomics.
// ---------------------------------------------------------------------------
template<int MODE, int MT, int NT, int CIN, int COUT, int LOGDI, int LOGDO, int SPLITK,
         int KT, bool STATS = false>
DEV void mfma_gemm_body(const ushort* __restrict__ xb, const ushort* __restrict__ wb,
                        float* __restrict__ y,
                        const float* __restrict__ bias = nullptr,
                        const float* __restrict__ m2 = nullptr,
                        float* __restrict__ part = nullptr) {
    constexpr int K  = (MODE == 1) ? CIN * 8 : CIN * 64;
    constexpr int KSEG = K / SPLITK;
    constexpr int OCT = KT / 8;                 // ushort8 loads per row per tile
    constexpr int LOGOCT = (KT == 32) ? 2 : 3;
    constexpr int KKN = KT / 32;                // mfma k-steps per tile
    constexpr int LDA = KT + 8;
    constexpr int MTW = MT / 32, NTW = NT / 32;
    constexpr int AR = MT * OCT / 256, BR = NT * OCT / 256;
    constexpr int LCIN = (CIN == 32) ? 5 : ((CIN == 64) ? 6 : 7);
    constexpr int Din = 1 << LOGDI, Do = 1 << LOGDO;
    constexpr int DvoxI = 1 << (3 * LOGDI), DvoxO = 1 << (3 * LOGDO);

    __shared__ __align__(16) ushort As[MT * LDA];
    __shared__ __align__(16) ushort Bs[NT * LDA];
    __shared__ float st[STATS ? COUT * 3 : 1];

    const int tid = threadIdx.x;
    const int bx = blockIdx.x;
    int pd = 0, ph = 0, pw = 0, ks = 0;
    const ushort* wp = wb;
    if constexpr (MODE == 1) {
        int z = blockIdx.z;
        pd = (z >> 2) & 1; ph = (z >> 1) & 1; pw = z & 1; ks = z >> 3;
        wp = wb + (size_t)(z & 7) * COUT * CIN * 8;
    } else {
        ks = blockIdx.z;
    }

    const int wv = tid >> 6, lane = tid & 63;
    const int mw = wv & 1, nw = wv >> 1;
    const int lr = lane & 15, quad = lane >> 4;

    if constexpr (STATS) {
        for (int i = tid; i < COUT * 3; i += 256) st[i] = 0.f;
        // visibility covered by the first __syncthreads of the K-loop
    }

    // hoisted per-slot B voxel decode
    int rB[BR], dB[BR], hB[BR], wBv[BR];
#pragma unroll
    for (int r = 0; r < BR; r++) {
        int slot = r * 256 + tid;
        int n = slot >> LOGOCT;
        int vg = bx * NT + n;
        if constexpr (MODE == 0) {
            rB[r] = vg >> (3 * LOGDO);
            int vv = vg & (DvoxO - 1);
            dB[r] = 2 * (vv >> (2 * LOGDO)) - 1;
            hB[r] = 2 * ((vv >> LOGDO) & (Do - 1)) - 1;
            wBv[r] = 2 * (vv & (Do - 1)) - 1;
        } else {
            rB[r] = vg >> (3 * LOGDI);
            int vv = vg & (DvoxI - 1);
            dB[r] = (vv >> (2 * LOGDI)) + pd - 1;
            hB[r] = ((vv >> LOGDI) & (Din - 1)) + ph - 1;
            wBv[r] = (vv & (Din - 1)) + pw - 1;
        }
    }

    auto gatherA = [&](int kt, ushort8* pa) {
#pragma unroll
        for (int r = 0; r < AR; r++) {
            int slot = r * 256 + tid;
            int m = slot >> LOGOCT, oct = slot & (OCT - 1);
            pa[r] = *(const ushort8*)&wp[(size_t)m * K + kt + oct * 8];
        }
    };
    // per-slot tap decode: a KT=64 tile may span 2 taps at CIN=32, but each
    // thread's ushort8 (8 k-values) is always within one tap (8 <= CIN).
    auto gatherB = [&](int kt, ushort8* pb) {
#pragma unroll
        for (int r = 0; r < BR; r++) {
            int oct = (r * 256 + tid) & (OCT - 1);
            int kk0 = kt + oct * 8;
            int tap = kk0 >> LCIN;
            int ci0 = kk0 & (CIN - 1);
            int id_d, ih_d, iw_d;
            if constexpr (MODE == 0) { id_d = tap >> 4; ih_d = (tap >> 2) & 3; iw_d = tap & 3; }
            else                     { id_d = (tap >> 2) & 1; ih_d = (tap >> 1) & 1; iw_d = tap & 1; }
            int id = dB[r] + id_d, ih = hB[r] + ih_d, iw = wBv[r] + iw_d;
            ushort8 v = (ushort8){0, 0, 0, 0, 0, 0, 0, 0};
            if ((unsigned)id < (unsigned)Din && (unsigned)ih < (unsigned)Din &&
                (unsigned)iw < (unsigned)Din)
                v = *(const ushort8*)&xb[((size_t)rB[r] * DvoxI +
                                          (id << (2 * LOGDI)) + (ih << LOGDI) + iw) * CIN + ci0];
            pb[r] = v;
        }
    };

    accv acc[MTW][NTW];
#pragma unroll
    for (int mt = 0; mt < MTW; mt++)
#pragma unroll
        for (int nt = 0; nt < NTW; nt++) acc[mt][nt] = (accv){0.f, 0.f, 0.f, 0.f};

    const int kbeg = ks * KSEG, kend = kbeg + KSEG;
    ushort8 pa[AR], pb[BR], qa[AR], qb[BR];
    gatherA(kbeg, pa);
    gatherB(kbeg, pb);

    for (int kt = kbeg; kt < kend; kt += KT) {
        __syncthreads();
#pragma unroll
        for (int r = 0; r < AR; r++) {
            int slot = r * 256 + tid;
            int m = slot >> LOGOCT, oct = slot & (OCT - 1);
            *(ushort8*)&As[m * LDA + oct * 8] = pa[r];
        }
#pragma unroll
        for (int r = 0; r < BR; r++) {
            int slot = r * 256 + tid;
            int n = slot >> LOGOCT, oct = slot & (OCT - 1);
            *(ushort8*)&Bs[n * LDA + oct * 8] = pb[r];
        }
        __syncthreads();
        bool more = (kt + KT) < kend;
        if (more) { gatherA(kt + KT, qa); gatherB(kt + KT, qb); }

        short8 af[MTW][KKN], bfr[NTW][KKN];
#pragma unroll
        for (int mt = 0; mt < MTW; mt++)
#pragma unroll
            for (int kk = 0; kk < KKN; kk++)
                af[mt][kk] = *(const short8*)&As[((mw * MTW + mt) * 16 + lr) * LDA +
                                                 kk * 32 + quad * 8];
#pragma unroll
        for (int nt = 0; nt < NTW; nt++)
#pragma unroll
            for (int kk = 0; kk < KKN; kk++)
                bfr[nt][kk] = *(const short8*)&Bs[((nw * NTW + nt) * 16 + lr) * LDA +
                                                  kk * 32 + quad * 8];
#pragma unroll
        for (int kk = 0; kk < KKN; kk++)
#pragma unroll
            for (int mt = 0; mt < MTW; mt++)
#pragma unroll
                for (int nt = 0; nt < NTW; nt++)
                    acc[mt][nt] = __builtin_amdgcn_mfma_f32_16x16x32_bf16(
                        af[mt][kk], bfr[nt][kk], acc[mt][nt], 0, 0, 0);
        if (more) {
#pragma unroll
            for (int r = 0; r < AR; r++) pa[r] = qa[r];
#pragma unroll
            for (int r = 0; r < BR; r++) pb[r] = qb[r];
        }
    }

    // ---- epilogue: scatter store (+ optional fused stats) ----
    float* yp = y + (size_t)ks * (2 * COUT * DvoxO);
    float sacc[MTW][4], s2acc[MTW][4], bco[MTW][4];
    float mvs = 0.f;
    if constexpr (STATS) {
#pragma unroll
        for (int mt = 0; mt < MTW; mt++)
#pragma unroll
            for (int r = 0; r < 4; r++) {
                sacc[mt][r] = 0.f; s2acc[mt][r] = 0.f;
                bco[mt][r] = bias[(mw * MTW + mt) * 16 + quad * 4 + r];
            }
    }
#pragma unroll
    for (int nt = 0; nt < NTW; nt++) {
        int vg = bx * NT + (nw * NTW + nt) * 16 + lr;
        int b, vvox;
        if constexpr (MODE == 1) {
            b = vg >> (3 * LOGDI);
            int vv = vg & (DvoxI - 1);
            int odp = vv >> (2 * LOGDI), ohp = (vv >> LOGDI) & (Din - 1), owp = vv & (Din - 1);
            vvox = ((2 * odp + pd) << (2 * LOGDO)) + ((2 * ohp + ph) << LOGDO) + (2 * owp + pw);
        } else {
            b = vg >> (3 * LOGDO);
            vvox = vg & (DvoxO - 1);
        }
        float mv = 0.f;
        if constexpr (STATS) {
            mv = m2[((size_t)b << (3 * LOGDO)) + vvox];
            mvs += mv;
        }
        size_t base = (((size_t)b * COUT) << (3 * LOGDO)) + vvox;
#pragma unroll
        for (int mt = 0; mt < MTW; mt++) {
#pragma unroll
            for (int r = 0; r < 4; r++) {
                int co = (mw * MTW + mt) * 16 + quad * 4 + r;
                float v = acc[mt][nt][r];
                yp[base + ((size_t)co << (3 * LOGDO))] = v;
                if constexpr (STATS) {
                    float yv = (v + bco[mt][r]) * mv;
                    yv = yv >= 0.f ? yv : 0.01f * yv;
                    sacc[mt][r] += yv; s2acc[mt][r] += yv * yv;
                }
            }
        }
    }

    if constexpr (STATS) {
#pragma unroll
        for (int mt = 0; mt < MTW; mt++)
#pragma unroll
            for (int r = 0; r < 4; r++) {
                float s = sacc[mt][r], s2 = s2acc[mt][r];
#pragma unroll
                for (int o = 8; o; o >>= 1) {
                    s  += __shfl_xor(s, o, 16);
                    s2 += __shfl_xor(s2, o, 16);
                }
                if (lr == 0) {
                    int co = (mw * MTW + mt) * 16 + quad * 4 + r;
                    atomicAdd(&st[co * 3 + 0], s);
                    atomicAdd(&st[co * 3 + 1], s2);
                }
            }
        float ms = mvs;
#pragma unroll
        for (int o = 8; o; o >>= 1) ms += __shfl_xor(ms, o, 16);
        if (lr == 0) {
#pragma unroll
            for (int mt = 0; mt < MTW; mt++)
#pragma unroll
                for (int r = 0; r < 4; r++)
                    atomicAdd(&st[((mw * MTW + mt) * 16 + quad * 4 + r) * 3 + 2], ms);
        }
        __syncthreads();
        // bucketed global accumulation: chain length = gridBlocks/64 per address
        int bucket = bx & 63;
        for (int i = tid; i < COUT * 3; i += 256)
            atomicAdd(&part[bucket * COUT * 3 + i], st[i]);
    }
}

__global__ __launch_bounds__(256)
void conv2_kernel() { mfma_gemm_body<0, 64, 64, 32, 64, 5, 4, 4, 64>(g_y1b, g_wb2, g_p2); }
__global__ __launch_bounds__(256)
void conv3_kernel() { mfma_gemm_body<0, 128, 64, 64, 128, 4, 3, 32, 64>(g_y2b, g_wb3, g_p3); }
__global__ __launch_bounds__(256)
void conv4_kernel() { mfma_gemm_body<1, 128, 64, 128, 128, 3, 4, 4, 64>(g_y3b, g_wb4, g_p4); }
__global__ __launch_bounds__(256)
void conv5_kernel(const float* __restrict__ b5) {
    // SPLITK=1 direct store + fused BN stats (replaces post5), bucketed atomics
    mfma_gemm_body<1, 64, 128, 128, 64, 4, 5, 1, 64, true>(g_t1b, g_wb5, g_t2,
                                                           b5, g_mt2, g_part5);
}

// ---------------------------------------------------------------------------
// conv1: bf16 MFMA, LDS-staged A, KT=64 (4 barrier iterations), fused BN
// stats (bucketed atomics x128, replaces stats1)
// ---------------------------------------------------------------------------
__global__ __launch_bounds__(256)
void conv1_kernel(const float* __restrict__ bias) {
    constexpr int LDA = 72;
    __shared__ __align__(16) ushort As[32 * LDA];
    __shared__ __align__(16) ushort Bs[64 * LDA];
    __shared__ float st[96];
    const int tid = threadIdx.x, bx = blockIdx.x;
    const int wv = tid >> 6, lane = tid & 63;
    const int lr = lane & 15, quad = lane >> 4;

    if (tid < 96) st[tid] = 0.f;

    // A: 32 rows x 8 octs = 256 slots, one per thread
    const int mA = tid >> 3, octA = tid & 7;

    // B: 64 rows x 8 octs = 512 slots, 2 per thread
    int nB[2], octB[2], bB[2], odB[2], ohB[2], owB[2];
#pragma unroll
    for (int r = 0; r < 2; r++) {
        int slot = r * 256 + tid;
        nB[r] = slot >> 3; octB[r] = slot & 7;
        int vg = bx * 64 + nB[r];
        bB[r] = vg >> 15; int vB = vg & 32767;
        odB[r] = vB >> 10; ohB[r] = (vB >> 5) & 31; owB[r] = vB & 31;
    }

    auto gatherA = [&](int kt, ushort8& pa) {
        pa = *(const ushort8*)&g_wb1[mA * 256 + kt + octA * 8];
    };
    auto gatherB = [&](int kt, ushort8* pb) {
#pragma unroll
        for (int r = 0; r < 2; r++) {
            int kg0 = kt + octB[r] * 8;
            int t0 = kg0 >> 2;                 // tap = k/4 (CIN=4)
            int kd = t0 >> 4, kh = (t0 >> 2) & 3, kw0 = t0 & 3;
            int id = 2 * odB[r] - 1 + kd;
            int ih = 2 * ohB[r] - 1 + kh;
            int iw0 = 2 * owB[r] - 1 + kw0;
            ushort8 v = (ushort8){0, 0, 0, 0, 0, 0, 0, 0};
            if ((unsigned)id < 64u && (unsigned)ih < 64u) {
                const ushort* base = g_x0b + ((((size_t)bB[r] << 18) + (id << 12) + (ih << 6)) << 2);
                if (iw0 >= 0 && iw0 + 1 < 64) {
                    v = *(const ushort8*)&base[iw0 << 2];
                } else {
                    if ((unsigned)iw0 < 64u) {
                        ushortx4 h = *(const ushortx4*)&base[iw0 << 2];
                        v[0] = h[0]; v[1] = h[1]; v[2] = h[2]; v[3] = h[3];
                    }
                    if ((unsigned)(iw0 + 1) < 64u) {
                        ushortx4 h = *(const ushortx4*)&base[(iw0 + 1) << 2];
                        v[4] = h[0]; v[5] = h[1]; v[6] = h[2]; v[7] = h[3];
                    }
                }
            }
            pb[r] = v;
        }
    };

    accv acc[2];
    acc[0] = (accv){0.f, 0.f, 0.f, 0.f};
    acc[1] = (accv){0.f, 0.f, 0.f, 0.f};
    ushort8 pa, qa, pb[2], qb[2];
    gatherA(0, pa); gatherB(0, pb);

    for (int kt = 0; kt < 256; kt += 64) {
        __syncthreads();
        *(ushort8*)&As[mA * LDA + octA * 8] = pa;
#pragma unroll
        for (int r = 0; r < 2; r++)
            *(ushort8*)&Bs[nB[r] * LDA + octB[r] * 8] = pb[r];
        __syncthreads();
        bool more = kt < 192;
        if (more) { gatherA(kt + 64, qa); gatherB(kt + 64, qb); }

#pragma unroll
        for (int kk = 0; kk < 2; kk++) {
            short8 b8 = *(const short8*)&Bs[(wv * 16 + lr) * LDA + kk * 32 + quad * 8];
#pragma unroll
            for (int mt = 0; mt < 2; mt++) {
                short8 a8 = *(const short8*)&As[(mt * 16 + lr) * LDA + kk * 32 + quad * 8];
                acc[mt] = __builtin_amdgcn_mfma_f32_16x16x32_bf16(a8, b8, acc[mt], 0, 0, 0);
            }
        }
        if (more) { pa = qa; pb[0] = qb[0]; pb[1] = qb[1]; }
    }

    // epilogue: bias+mask+leaky, store y1, fused stats (replaces stats1)
    int vg = bx * 64 + wv * 16 + lr;
    int b = vg >> 15, off = vg & 32767;
    float mv = g_m1[((size_t)b << 15) + off];
    float sacc[2][4], s2acc[2][4];
#pragma unroll
    for (int mt = 0; mt < 2; mt++) {
#pragma unroll
        for (int r = 0; r < 4; r++) {
            int co = mt * 16 + quad * 4 + r;
            float yv = (acc[mt][r] + bias[co]) * mv;
            yv = yv >= 0.f ? yv : 0.01f * yv;
            g_y1[(((size_t)(b * 32 + co)) << 15) + off] = yv;
            sacc[mt][r] = yv; s2acc[mt][r] = yv * yv;
        }
    }
#pragma unroll
    for (int mt = 0; mt < 2; mt++) {
#pragma unroll
        for (int r = 0; r < 4; r++) {
            float s = sacc[mt][r], s2 = s2acc[mt][r];
#pragma unroll
            for (int o = 8; o; o >>= 1) {
                s  += __shfl_xor(s, o, 16);
                s2 += __shfl_xor(s2, o, 16);
            }
            if (lr == 0) {
                int co = mt * 16 + quad * 4 + r;
                atomicAdd(&st[co * 3 + 0], s);
                atomicAdd(&st[co * 3 + 1], s2);
            }
        }
    }
    float ms = mv;
#pragma unroll
    for (int o = 8; o; o >>= 1) ms += __shfl_xor(ms, o, 16);
    if (lr == 0) {
#pragma unroll
        for (int mt = 0; mt < 2; mt++)
#pragma unroll
            for (int r = 0; r < 4; r++)
                atomicAdd(&st[(mt * 16 + quad * 4 + r) * 3 + 2], ms);
    }
    __syncthreads();
    // bucketed global accumulation: chain length = 1024/128 = 8 per address
    if (tid < 96) atomicAdd(&g_part1[(bx & 127) * 96 + tid], st[tid]);
}

// ---------------------------------------------------------------------------
// final: fp32 1x1x1, fully fused load: bias5+mask+leaky+BN. grid 1024.
// BN scales derived by summing g_part5 buckets.
// ---------------------------------------------------------------------------
__global__ __launch_bounds__(256)
void final_kernel(const float* __restrict__ fb, const float* __restrict__ b5,
                  const float* __restrict__ tg2, const float* __restrict__ tbe2,
                  float* __restrict__ out) {
    __shared__ float As[1024];
    __shared__ float Bs[2048];
    __shared__ float sc5[64], sh5[64], bb5[64];
    const int tid = threadIdx.x, tc = tid & 15, tv = tid >> 4;
    const int bx = blockIdx.x;

    if (tid < 64) {
        float s0 = 0.f, s1 = 0.f, cnt = 0.f;
#pragma unroll 4
        for (int bkt = 0; bkt < 64; bkt++) {
            const float* p = g_part5 + bkt * 192 + tid * 3;
            s0 += p[0]; s1 += p[1]; cnt += p[2];
        }
        float n = fmaxf(cnt, 1.f);
        float mean = s0 / n;
        float var = fmaxf(s1 / n - mean * mean, 0.f);
        float rstd = rsqrtf(var + 1e-5f);
        float s = tg2[tid] * rstd;
        sc5[tid] = s; sh5[tid] = tbe2[tid] - mean * s; bb5[tid] = b5[tid];
    }

    float acc[2][4] = {{0.f}};
    for (int kt = 0; kt < 64; kt += 32) {
        __syncthreads();
#pragma unroll
        for (int e = 0; e < 4; e++) As[e * 256 + tid] = g_fwt[kt * 32 + e * 256 + tid];
#pragma unroll
        for (int e = 0; e < 8; e++) {
            int j = e * 256 + tid;
            int kk = j >> 6, n = j & 63;
            int kg = kt + kk;
            int vg = bx * 64 + n;
            int b = vg >> 15, v = vg & 32767;
            float raw = g_t2[(((size_t)(b * 64 + kg)) << 15) + v];
            float mv = g_mt2[((size_t)b << 15) + v];
            float t = (raw + bb5[kg]) * mv;
            t = t >= 0.f ? t : 0.01f * t;
            Bs[kk * 64 + n] = (t * sc5[kg] + sh5[kg]) * mv;
        }
        __syncthreads();
#pragma unroll
        for (int kk = 0; kk < 32; kk++) {
            float2 a2 = *(const float2*)&As[kk * 32 + tc * 2];
            float4 b4 = *(const float4*)&Bs[kk * 64 + tv * 4];
            float a[2] = {a2.x, a2.y};
            float bb[4] = {b4.x, b4.y, b4.z, b4.w};
#pragma unroll
            for (int r = 0; r < 2; r++)
#pragma unroll
                for (int c = 0; c < 4; c++) acc[r][c] = fmaf(a[r], bb[c], acc[r][c]);
        }
    }
#pragma unroll
    for (int r = 0; r < 2; r++) {
        int co = tc * 2 + r;
        float bv = fb[co];
#pragma unroll
        for (int c = 0; c < 4; c++) {
            int vg = bx * 64 + tv * 4 + c;
            int b = vg >> 15, v = vg & 32767;
            out[(((size_t)(b * 32 + co)) << 15) + v] = acc[r][c] + bv;
        }
    }
}

// ---------------------------------------------------------------------------
DEV void red3_and_atomic(float s, float s2, float sm, float* sred, int co) {
#pragma unroll
    for (int off = 32; off; off >>= 1) {
        s  += __shfl_down(s, off, 64);
        s2 += __shfl_down(s2, off, 64);
        sm += __shfl_down(sm, off, 64);
    }
    __shared__ float red[12];
    int lane = threadIdx.x & 63, wvi = threadIdx.x >> 6;
    if (!lane) { red[wvi] = s; red[4 + wvi] = s2; red[8 + wvi] = sm; }
    __syncthreads();
    if (!threadIdx.x) {
        atomicAdd(&sred[co * 32 + 0], red[0] + red[1] + red[2] + red[3]);
        atomicAdd(&sred[co * 32 + 1], red[4] + red[5] + red[6] + red[7]);
        atomicAdd(&sred[co * 32 + 2], red[8] + red[9] + red[10] + red[11]);
    }
}

// ---------------------------------------------------------------------------
// post: sum SPLITK partials + bias + mask + LeakyReLU + stats
// ---------------------------------------------------------------------------
template<int COUT, int LOGDO, int SPLITK, int ITERS, bool WRITE>
DEV void post_body(const float* __restrict__ bias, const float* __restrict__ m2,
                   const float* p, float* y, float* sred) {
    constexpr int Dvox = 1 << (3 * LOGDO);
    constexpr size_t STR = (size_t)2 * COUT * Dvox;
    constexpr int LOGC = (COUT == 128) ? 7 : ((COUT == 64) ? 6 : 5);
    int base = blockIdx.x * (ITERS * 256);
    int co = (base >> (3 * LOGDO)) & (COUT - 1);
    float s = 0.f, s2 = 0.f, sm = 0.f;
#pragma unroll
    for (int it = 0; it < ITERS; it++) {
        int idx = base + it * 256 + threadIdx.x;
        int v = idx & (Dvox - 1);
        int b = idx >> (3 * LOGDO + LOGC);
        float sum = 0.f;
#pragma unroll
        for (int k = 0; k < SPLITK; k++) sum += p[k * STR + idx];
        float mv = m2[((size_t)b << (3 * LOGDO)) + v];
        float yv = (sum + bias[co]) * mv;
        yv = yv >= 0.f ? yv : 0.01f * yv;
        if constexpr (WRITE) y[idx] = yv;
        s += yv; s2 += yv * yv; sm += mv;
    }
    red3_and_atomic(s, s2, sm, sred, co);
}

__global__ __launch_bounds__(256) void post2_kernel(const float* b) { post_body<64, 4, 4, 1, true>(b, g_m2, g_p2, g_y2, g_sred + 4096); }
__global__ __launch_bounds__(256) void post3_kernel(const float* b) { post_body<128, 3, 32, 1, true>(b, g_m3, g_p3, g_y3, g_sred + 8192); }
__global__ __launch_bounds__(256) void post4_kernel(const float* b) { post_body<128, 4, 4, 2, true>(b, g_mt1, g_p4, g_t1, g_sred + 12288); }

// ---------------------------------------------------------------------------
// bn fused with finalize, explicit block index.
// PART>0: derive scales by summing PART stat buckets [bkt][C*3] (conv1 path).
// PART==0: classic g_sred layout [co*32 + s].
// ---------------------------------------------------------------------------
template<int LOGC, int LOGD, int PART>
DEV void bn_fused_body(const float* __restrict__ y, ushort* __restrict__ out,
                       const float* __restrict__ sred, const float* __restrict__ gm,
                       const float* __restrict__ be, const float* __restrict__ m2,
                       int blk) {
    constexpr int C = 1 << LOGC, Dvox = 1 << LOGD;
    __shared__ float sc[C], sh[C];
    int tid = threadIdx.x;
    if (tid < C) {
        float s0, s1, cnt;
        if constexpr (PART > 0) {
            s0 = 0.f; s1 = 0.f; cnt = 0.f;
#pragma unroll 4
            for (int bkt = 0; bkt < PART; bkt++) {
                const float* p = sred + bkt * C * 3 + tid * 3;
                s0 += p[0]; s1 += p[1]; cnt += p[2];
            }
        } else {
            s0 = sred[tid * 32]; s1 = sred[tid * 32 + 1]; cnt = sred[tid * 32 + 2];
        }
        float n = fmaxf(cnt, 1.f);
        float mean = s0 / n;
        float var = fmaxf(s1 / n - mean * mean, 0.f);
        float rstd = rsqrtf(var + 1e-5f);
        float s = gm[tid] * rstd;
        sc[tid] = s; sh[tid] = be[tid] - mean * s;
    }
    __syncthreads();
    int gv = blk * 256 + tid;
    int b = gv >> LOGD, vox = gv & (Dvox - 1);
    float mv = m2[gv];
    const float* yp = y + (((size_t)b << LOGC) << LOGD) + vox;
    ushort* op = out + (size_t)gv * C;
#pragma unroll
    for (int c0 = 0; c0 < C; c0 += 8) {
        ushort pk[8];
#pragma unroll
        for (int j = 0; j < 8; j++) {
            int c = c0 + j;
            float val = yp[(size_t)c << LOGD];
            pk[j] = f2bf((val * sc[c] + sh[c]) * mv);
        }
        *(ushort8*)&op[c0] = (ushort8){pk[0], pk[1], pk[2], pk[3], pk[4], pk[5], pk[6], pk[7]};
    }
}

// bn kernels with fused next-mask blocks
__global__ __launch_bounds__(256)
void bn1_kernel(const float* g, const float* be) {          // grid 288
    if (blockIdx.x < 256) bn_fused_body<5, 15, 128>(g_y1, g_y1b, g_part1, g, be, g_m1, blockIdx.x);
    else mask_down_blk(g_m1, g_m2, 5, 4, blockIdx.x - 256); // mask2: 32 blocks
}
__global__ __launch_bounds__(256)
void bn2_kernel(const float* g, const float* be) {          // grid 36
    if (blockIdx.x < 32) bn_fused_body<6, 12, 0>(g_y2, g_y2b, g_sred + 4096, g, be, g_m2, blockIdx.x);
    else mask_down_blk(g_m2, g_m3, 4, 3, blockIdx.x - 32);  // mask3: 4 blocks
}
__global__ __launch_bounds__(256)
void bn3_kernel(const float* g, const float* be) {          // grid 36
    if (blockIdx.x < 4) bn_fused_body<7, 9, 0>(g_y3, g_y3b, g_sred + 8192, g, be, g_m3, blockIdx.x);
    else mask_up_blk(g_m3, g_mt1, 3, 4, blockIdx.x - 4);    // mask4: 32 blocks
}
__global__ __launch_bounds__(256)
void bn4_kernel(const float* g, const float* be) {          // grid 288
    if (blockIdx.x < 32) bn_fused_body<7, 12, 0>(g_t1, g_t1b, g_sred + 12288, g, be, g_mt1, blockIdx.x);
    else mask_up_blk(g_mt1, g_mt2, 4, 5, blockIdx.x - 32);  // mask5: 256 blocks
}

// ---------------------------------------------------------------------------

extern "C" void kernel_launch(void* const* d_in, const int* in_sizes, int n_in,
                              void* d_out, int out_size, void* d_ws, size_t ws_size,
                              hipStream_t stream) {
    (void)in_sizes; (void)n_in; (void)out_size; (void)d_ws; (void)ws_size;
    const float* feat = (const float*)d_in[0];
    const float* mask = (const float*)d_in[1];
    const float* w1  = (const float*)d_in[2];
    const float* b1  = (const float*)d_in[3];
    const float* g1  = (const float*)d_in[4];
    const float* be1 = (const float*)d_in[5];
    const float* w2  = (const float*)d_in[6];
    const float* b2  = (const float*)d_in[7];
    const float* g2  = (const float*)d_in[8];
    const float* be2 = (const float*)d_in[9];
    const float* w3  = (const float*)d_in[10];
    const float* b3  = (const float*)d_in[11];
    const float* g3  = (const float*)d_in[12];
    const float* be3 = (const float*)d_in[13];
    const float* tw1 = (const float*)d_in[14];
    const float* tb1 = (const float*)d_in[15];
    const float* tg1 = (const float*)d_in[16];
    const float* tbe1= (const float*)d_in[17];
    const float* tw2 = (const float*)d_in[18];
    const float* tb2 = (const float*)d_in[19];
    const float* tg2 = (const float*)d_in[20];
    const float* tbe2= (const float*)d_in[21];
    const float* fw  = (const float*)d_in[22];
    const float* fb  = (const float*)d_in[23];

    prep_all_kernel<<<11104, 256, 0, stream>>>(w1, fw, w2, w3, tw1, tw2, feat, mask);

    // block 1 (bf16 MFMA + fused stats): 4->32, 64^3 -> 32^3, KT=64
    conv1_kernel<<<1024, 256, 0, stream>>>(b1);
    bn1_kernel<<<288, 256, 0, stream>>>(g1, be1);          // + mask2

    // block 2 (MFMA): 32->64, 32^3 -> 16^3, K=2048 split 4, NT=64, KT=64
    conv2_kernel<<<dim3(128, 1, 4), 256, 0, stream>>>();
    post2_kernel<<<2048, 256, 0, stream>>>(b2);
    bn2_kernel<<<36, 256, 0, stream>>>(g2, be2);           // + mask3

    // block 3 (MFMA): 64->128, 16^3 -> 8^3, K=4096 split 32, KT=64
    conv3_kernel<<<dim3(16, 1, 32), 256, 0, stream>>>();
    post3_kernel<<<512, 256, 0, stream>>>(b3);
    bn3_kernel<<<36, 256, 0, stream>>>(g3, be3);           // + mask4

    // up block 1 (MFMA): 128->128, 8^3 -> 16^3, parity 8 x split 4, NT=64, KT=64
    conv4_kernel<<<dim3(16, 1, 32), 256, 0, stream>>>();
    post4_kernel<<<2048, 256, 0, stream>>>(tb1);
    bn4_kernel<<<288, 256, 0, stream>>>(tg1, tbe1);        // + mask5

    // up block 2 (MFMA): 128->64, 16^3 -> 32^3, parity 8, KT=64, direct store + fused stats
    conv5_kernel<<<dim3(64, 1, 8), 256, 0, stream>>>(tb2);

    // final dense 1x1x1 conv 64->32 @ 32^3 (bias5+mask+leaky+BN fused on load)
    final_kernel<<<1024, 256, 0, stream>>>(fb, tb2, tg2, tbe2, (float*)d_out);
}

// Round 7
// 264.499 us; speedup vs baseline: 1.0311x; 1.0311x over previous
//
#include <hip/hip_runtime.h>
#include <hip/hip_bf16.h>

#define DEV static __device__ __forceinline__

typedef unsigned short ushort;
typedef __attribute__((ext_vector_type(8))) short short8;
typedef __attribute__((ext_vector_type(8))) ushort ushort8;
typedef __attribute__((ext_vector_type(4))) ushort ushortx4;
typedef __attribute__((ext_vector_type(4))) float accv;

DEV ushort f2bf(float f) {
    __hip_bfloat16 h = __float2bfloat16(f);   // RNE
    return reinterpret_cast<ushort&>(h);
}

// ---------------------------------------------------------------------------
// Static device workspace
// ---------------------------------------------------------------------------
__device__ float    g_sred[5 * 128 * 32];             // [l][co][32]: 0=sum 1=sumsq 2=maskcnt
__device__ float    g_part1[128 * 96];                // conv1 bucketed stats [bkt][co*3+s]
__device__ float    g_part5[64 * 192];                // conv5 bucketed stats [bkt][co*3+s]
__device__ float    g_y1[2097152];                    // (2,32,32^3) fp32 NCV
__device__ __align__(16) ushort g_y1b[2097152];       // (2,32^3,32) bf16 VC
__device__ float    g_m1[65536];
__device__ float    g_y2[524288];
__device__ __align__(16) ushort g_y2b[524288];        // (2,16^3,64) bf16 VC
__device__ float    g_m2[8192];
__device__ float    g_y3[131072];
__device__ __align__(16) ushort g_y3b[131072];        // (2,8^3,128) bf16 VC
__device__ float    g_m3[1024];
__device__ float    g_t1[1048576];
__device__ __align__(16) ushort g_t1b[1048576];       // (2,16^3,128) bf16 VC
__device__ float    g_mt1[8192];
__device__ float    g_mt2[65536];
__device__ float    g_t2[4194304];                    // conv5 raw out (fp32 NCV)
__device__ __align__(16) ushort g_x0b[2097152];       // (2,64^3,4) bf16 VC masked feat
// split-K partial buffers
__device__ float    g_p2[4194304];                    // 4  x 524288 used
__device__ float    g_p3[4194304];                    // 32 x 131072
__device__ float    g_p4[8388608];                    // 4  x 1048576 used
// K-major weights
__device__ __align__(16) ushort g_wb1[8192];          // [32co][256k] bf16, k=tap*4+ci
__device__ __align__(16) ushort g_wb2[131072];
__device__ __align__(16) ushort g_wb3[524288];
__device__ __align__(16) ushort g_wb4[1048576];
__device__ __align__(16) ushort g_wb5[524288];
__device__ float    g_fwt[2048];                      // [k=64][co=32] fp32

// ---------------------------------------------------------------------------
// prep_all (verified round-11/12)
// ---------------------------------------------------------------------------
__global__ __launch_bounds__(256)
void prep_all_kernel(const float* __restrict__ w1, const float* __restrict__ fw,
                     const float* __restrict__ w2, const float* __restrict__ w3,
                     const float* __restrict__ tw1, const float* __restrict__ tw2,
                     const float* __restrict__ feat, const float* __restrict__ mask) {
    int blk = blockIdx.x, tid = threadIdx.x;
    if (blk < 96) {
        int idx = blk * 256 + tid;
        if (idx < 20480) g_sred[idx] = 0.f;
        if (idx < 12288) g_part1[idx] = 0.f;
        if (idx < 12288) g_part5[idx] = 0.f;
        if (idx < 8192) {
            int co = idx >> 8, r = idx & 255;
            int tap = r >> 2, ci = r & 3;
            g_wb1[idx] = f2bf(w1[co * 256 + ci * 64 + tap]);
        }
        if (idx < 2048) { int co = idx >> 6, kg = idx & 63; g_fwt[kg * 32 + co] = fw[idx]; }
    } else if (blk < 608) {
        int idx = (blk - 96) * 256 + tid;
        int co = idx / 2048, r = idx % 2048;
        int ci = r >> 6, tap = r & 63;
        g_wb2[(size_t)co * 2048 + tap * 32 + ci] = f2bf(w2[idx]);
    } else if (blk < 2656) {
        int idx = (blk - 608) * 256 + tid;
        int co = idx / 4096, r = idx % 4096;
        int ci = r >> 6, tap = r & 63;
        g_wb3[(size_t)co * 4096 + tap * 64 + ci] = f2bf(w3[idx]);
    } else if (blk < 6752) {
        int idx = (blk - 2656) * 256 + tid;
        int co = idx / 8192, r = idx % 8192;
        int ci = r >> 6, t64 = r & 63;
        int kd = t64 >> 4, kh = (t64 >> 2) & 3, kw = t64 & 3;
        int pd = (3 - kd) & 1, td = (3 - kd) >> 1;
        int ph = (3 - kh) & 1, th = (3 - kh) >> 1;
        int pw = (3 - kw) & 1, tw = (3 - kw) >> 1;
        int parity = pd * 4 + ph * 2 + pw, t = td * 4 + th * 2 + tw;
        g_wb4[(((size_t)parity * 128 + co) * 8 + t) * 128 + ci] = f2bf(tw1[idx]);
    } else if (blk < 8800) {
        int idx = (blk - 6752) * 256 + tid;
        int co = idx / 8192, r = idx % 8192;
        int ci = r >> 6, t64 = r & 63;
        int kd = t64 >> 4, kh = (t64 >> 2) & 3, kw = t64 & 3;
        int pd = (3 - kd) & 1, td = (3 - kd) >> 1;
        int ph = (3 - kh) & 1, th = (3 - kh) >> 1;
        int pw = (3 - kw) & 1, tw = (3 - kw) >> 1;
        int parity = pd * 4 + ph * 2 + pw, t = td * 4 + th * 2 + tw;
        g_wb5[(((size_t)parity * 64 + co) * 8 + t) * 128 + ci] = f2bf(tw2[idx]);
    } else if (blk < 10848) {
        int idx = (blk - 8800) * 256 + tid;
        int b = idx >> 18, v = idx & 0x3FFFF;
        float mv = mask[idx] > 0.5f ? 1.f : 0.f;
        ushort pk[4];
#pragma unroll
        for (int c = 0; c < 4; c++) pk[c] = f2bf(feat[((b * 4 + c) << 18) + v] * mv);
        *(ushortx4*)&g_x0b[(size_t)idx * 4] = (ushortx4){pk[0], pk[1], pk[2], pk[3]};
    } else {
        int idx = (blk - 10848) * 256 + tid;            // mask1: 65536
        int b = idx >> 15, v = idx & 0x7FFF;
        int od = v >> 10, rem = v & 1023;
        int oh = rem >> 5, ow = rem & 31;
        const float* mp = mask + ((size_t)b << 18);
        float acc = 0.f;
        for (int kd = 0; kd < 4; kd++) {
            int id = 2 * od - 1 + kd;
            if ((unsigned)id >= 64u) continue;
            for (int kh = 0; kh < 4; kh++) {
                int ih = 2 * oh - 1 + kh;
                if ((unsigned)ih >= 64u) continue;
                const float* row = mp + ((size_t)id * 64 + ih) * 64;
                for (int kw = 0; kw < 4; kw++) {
                    int iw = 2 * ow - 1 + kw;
                    if ((unsigned)iw < 64u && row[iw] > 0.5f) acc += 1.f;
                }
            }
        }
        g_m1[idx] = acc > 0.f ? 1.f : 0.f;
    }
}

// ---------------------------------------------------------------------------
// mask dilation bodies with explicit block index (fused into bn kernels)
// ---------------------------------------------------------------------------
DEV void mask_down_blk(const float* mprev, float* mout, int logDin, int logDo, int blk) {
    int Din = 1 << logDin, Do = 1 << logDo;
    int idx = blk * 256 + threadIdx.x;
    int b = idx >> (3 * logDo), v = idx & ((1 << (3 * logDo)) - 1);
    int od = v >> (2 * logDo), rem = v & ((1 << (2 * logDo)) - 1);
    int oh = rem >> logDo, ow = rem & (Do - 1);
    const float* mp = mprev + ((size_t)b << (3 * logDin));
    float acc = 0.f;
    for (int kd = 0; kd < 4; kd++) {
        int id = 2 * od - 1 + kd;
        if ((unsigned)id >= (unsigned)Din) continue;
        for (int kh = 0; kh < 4; kh++) {
            int ih = 2 * oh - 1 + kh;
            if ((unsigned)ih >= (unsigned)Din) continue;
            const float* row = mp + ((size_t)id * Din + ih) * Din;
            for (int kw = 0; kw < 4; kw++) {
                int iw = 2 * ow - 1 + kw;
                if ((unsigned)iw < (unsigned)Din) acc += row[iw];
            }
        }
    }
    mout[idx] = acc > 0.f ? 1.f : 0.f;
}

DEV void mask_up_blk(const float* mprev, float* mout, int logDin, int logDo, int blk) {
    int Din = 1 << logDin, Do = 1 << logDo;
    int idx = blk * 256 + threadIdx.x;
    int b = idx >> (3 * logDo), v = idx & ((1 << (3 * logDo)) - 1);
    int od = v >> (2 * logDo), rem = v & ((1 << (2 * logDo)) - 1);
    int oh = rem >> logDo, ow = rem & (Do - 1);
    const float* mp = mprev + ((size_t)b << (3 * logDin));
    float acc = 0.f;
    for (int kd = 0; kd < 4; kd++) {
        int u = od + kd - 2; if (u < 0 || (u & 1)) continue;
        int id = u >> 1; if (id >= Din) continue;
        for (int kh = 0; kh < 4; kh++) {
            int uh = oh + kh - 2; if (uh < 0 || (uh & 1)) continue;
            int ih = uh >> 1; if (ih >= Din) continue;
            const float* row = mp + ((size_t)id * Din + ih) * Din;
            for (int kw = 0; kw < 4; kw++) {
                int uw = ow + kw - 2; if (uw < 0 || (uw & 1)) continue;
                int iw = uw >> 1; if (iw >= Din) continue;
                acc += row[iw];
            }
        }
    }
    mout[idx] = acc > 0.f ? 1.f : 0.f;
}

// ---------------------------------------------------------------------------
// bf16 MFMA implicit-GEMM, DOUBLE-BUFFERED LDS: one barrier per K-iteration.
// WAR-safe: stage(cur^1) writes a buffer whose last readers were separated
// by the barrier at the end of the previous iteration. 2x LDS costs zero
// occupancy (all GEMMs are grid-limited to 2 blocks/CU; 110KB < 160KB).
// Per-slot tap decode in gatherB makes KT=64 legal for any CIN >= 8.
// Optional fused BN-stats epilogue (STATS): bucketed global atomics.
// ---------------------------------------------------------------------------
template<int MODE, int MT, int NT, int CIN, int COUT, int LOGDI, int LOGDO, int SPLITK,
         int KT, bool STATS = false>
DEV void mfma_gemm_body(const ushort* __restrict__ xb, const ushort* __restrict__ wb,
                        float* __restrict__ y,
                        const float* __restrict__ bias = nullptr,
                        const float* __restrict__ m2 = nullptr,
                        float* __restrict__ part = nullptr) {
    constexpr int K  = (MODE == 1) ? CIN * 8 : CIN * 64;
    constexpr int KSEG = K / SPLITK;
    constexpr int OCT = KT / 8;                 // ushort8 loads per row per tile
    constexpr int LOGOCT = (KT == 32) ? 2 : 3;
    constexpr int KKN = KT / 32;                // mfma k-steps per tile
    constexpr int LDA = KT + 8;
    constexpr int MTW = MT / 32, NTW = NT / 32;
    constexpr int AR = MT * OCT / 256, BR = NT * OCT / 256;
    constexpr int LCIN = (CIN == 32) ? 5 : ((CIN == 64) ? 6 : 7);
    constexpr int Din = 1 << LOGDI, Do = 1 << LOGDO;
    constexpr int DvoxI = 1 << (3 * LOGDI), DvoxO = 1 << (3 * LOGDO);

    __shared__ __align__(16) ushort As[2][MT * LDA];
    __shared__ __align__(16) ushort Bs[2][NT * LDA];
    __shared__ float st[STATS ? COUT * 3 : 1];

    const int tid = threadIdx.x;
    const int bx = blockIdx.x;
    int pd = 0, ph = 0, pw = 0, ks = 0;
    const ushort* wp = wb;
    if constexpr (MODE == 1) {
        int z = blockIdx.z;
        pd = (z >> 2) & 1; ph = (z >> 1) & 1; pw = z & 1; ks = z >> 3;
        wp = wb + (size_t)(z & 7) * COUT * CIN * 8;
    } else {
        ks = blockIdx.z;
    }

    const int wv = tid >> 6, lane = tid & 63;
    const int mw = wv & 1, nw = wv >> 1;
    const int lr = lane & 15, quad = lane >> 4;

    if constexpr (STATS) {
        for (int i = tid; i < COUT * 3; i += 256) st[i] = 0.f;
        // visibility covered by the prologue __syncthreads
    }

    // hoisted per-slot B voxel decode
    int rB[BR], dB[BR], hB[BR], wBv[BR];
#pragma unroll
    for (int r = 0; r < BR; r++) {
        int slot = r * 256 + tid;
        int n = slot >> LOGOCT;
        int vg = bx * NT + n;
        if constexpr (MODE == 0) {
            rB[r] = vg >> (3 * LOGDO);
            int vv = vg & (DvoxO - 1);
            dB[r] = 2 * (vv >> (2 * LOGDO)) - 1;
            hB[r] = 2 * ((vv >> LOGDO) & (Do - 1)) - 1;
            wBv[r] = 2 * (vv & (Do - 1)) - 1;
        } else {
            rB[r] = vg >> (3 * LOGDI);
            int vv = vg & (DvoxI - 1);
            dB[r] = (vv >> (2 * LOGDI)) + pd - 1;
            hB[r] = ((vv >> LOGDI) & (Din - 1)) + ph - 1;
            wBv[r] = (vv & (Din - 1)) + pw - 1;
        }
    }

    auto gatherA = [&](int kt, ushort8* pa) {
#pragma unroll
        for (int r = 0; r < AR; r++) {
            int slot = r * 256 + tid;
            int m = slot >> LOGOCT, oct = slot & (OCT - 1);
            pa[r] = *(const ushort8*)&wp[(size_t)m * K + kt + oct * 8];
        }
    };
    // per-slot tap decode: a KT=64 tile may span 2 taps at CIN=32, but each
    // thread's ushort8 (8 k-values) is always within one tap (8 <= CIN).
    auto gatherB = [&](int kt, ushort8* pb) {
#pragma unroll
        for (int r = 0; r < BR; r++) {
            int oct = (r * 256 + tid) & (OCT - 1);
            int kk0 = kt + oct * 8;
            int tap = kk0 >> LCIN;
            int ci0 = kk0 & (CIN - 1);
            int id_d, ih_d, iw_d;
            if constexpr (MODE == 0) { id_d = tap >> 4; ih_d = (tap >> 2) & 3; iw_d = tap & 3; }
            else                     { id_d = (tap >> 2) & 1; ih_d = (tap >> 1) & 1; iw_d = tap & 1; }
            int id = dB[r] + id_d, ih = hB[r] + ih_d, iw = wBv[r] + iw_d;
            ushort8 v = (ushort8){0, 0, 0, 0, 0, 0, 0, 0};
            if ((unsigned)id < (unsigned)Din && (unsigned)ih < (unsigned)Din &&
                (unsigned)iw < (unsigned)Din)
                v = *(const ushort8*)&xb[((size_t)rB[r] * DvoxI +
                                          (id << (2 * LOGDI)) + (ih << LOGDI) + iw) * CIN + ci0];
            pb[r] = v;
        }
    };
    auto stage = [&](int buf, ushort8* a, ushort8* b) {
#pragma unroll
        for (int r = 0; r < AR; r++) {
            int slot = r * 256 + tid;
            int m = slot >> LOGOCT, oct = slot & (OCT - 1);
            *(ushort8*)&As[buf][m * LDA + oct * 8] = a[r];
        }
#pragma unroll
        for (int r = 0; r < BR; r++) {
            int slot = r * 256 + tid;
            int n = slot >> LOGOCT, oct = slot & (OCT - 1);
            *(ushort8*)&Bs[buf][n * LDA + oct * 8] = b[r];
        }
    };

    accv acc[MTW][NTW];
#pragma unroll
    for (int mt = 0; mt < MTW; mt++)
#pragma unroll
        for (int nt = 0; nt < NTW; nt++) acc[mt][nt] = (accv){0.f, 0.f, 0.f, 0.f};

    const int kbeg = ks * KSEG, kend = kbeg + KSEG;
    ushort8 pa[AR], pb[BR], qa[AR], qb[BR];
    gatherA(kbeg, pa);
    gatherB(kbeg, pb);
    stage(0, pa, pb);
    __syncthreads();

    int cur = 0;
    for (int kt = kbeg; kt < kend; kt += KT) {
        bool more = (kt + KT) < kend;
        if (more) { gatherA(kt + KT, qa); gatherB(kt + KT, qb); }

        short8 af[MTW][KKN], bfr[NTW][KKN];
#pragma unroll
        for (int mt = 0; mt < MTW; mt++)
#pragma unroll
            for (int kk = 0; kk < KKN; kk++)
                af[mt][kk] = *(const short8*)&As[cur][((mw * MTW + mt) * 16 + lr) * LDA +
                                                     kk * 32 + quad * 8];
#pragma unroll
        for (int nt = 0; nt < NTW; nt++)
#pragma unroll
            for (int kk = 0; kk < KKN; kk++)
                bfr[nt][kk] = *(const short8*)&Bs[cur][((nw * NTW + nt) * 16 + lr) * LDA +
                                                      kk * 32 + quad * 8];
#pragma unroll
        for (int kk = 0; kk < KKN; kk++)
#pragma unroll
            for (int mt = 0; mt < MTW; mt++)
#pragma unroll
                for (int nt = 0; nt < NTW; nt++)
                    acc[mt][nt] = __builtin_amdgcn_mfma_f32_16x16x32_bf16(
                        af[mt][kk], bfr[nt][kk], acc[mt][nt], 0, 0, 0);
        if (more) {
            stage(cur ^ 1, qa, qb);
            __syncthreads();
            cur ^= 1;
        }
    }

    // ---- epilogue: scatter store (+ optional fused stats) ----
    float* yp = y + (size_t)ks * (2 * COUT * DvoxO);
    float sacc[MTW][4], s2acc[MTW][4], bco[MTW][4];
    float mvs = 0.f;
    if constexpr (STATS) {
#pragma unroll
        for (int mt = 0; mt < MTW; mt++)
#pragma unroll
            for (int r = 0; r < 4; r++) {
                sacc[mt][r] = 0.f; s2acc[mt][r] = 0.f;
                bco[mt][r] = bias[(mw * MTW + mt) * 16 + quad * 4 + r];
            }
    }
#pragma unroll
    for (int nt = 0; nt < NTW; nt++) {
        int vg = bx * NT + (nw * NTW + nt) * 16 + lr;
        int b, vvox;
        if constexpr (MODE == 1) {
            b = vg >> (3 * LOGDI);
            int vv = vg & (DvoxI - 1);
            int odp = vv >> (2 * LOGDI), ohp = (vv >> LOGDI) & (Din - 1), owp = vv & (Din - 1);
            vvox = ((2 * odp + pd) << (2 * LOGDO)) + ((2 * ohp + ph) << LOGDO) + (2 * owp + pw);
        } else {
            b = vg >> (3 * LOGDO);
            vvox = vg & (DvoxO - 1);
        }
        float mv = 0.f;
        if constexpr (STATS) {
            mv = m2[((size_t)b << (3 * LOGDO)) + vvox];
            mvs += mv;
        }
        size_t base = (((size_t)b * COUT) << (3 * LOGDO)) + vvox;
#pragma unroll
        for (int mt = 0; mt < MTW; mt++) {
#pragma unroll
            for (int r = 0; r < 4; r++) {
                int co = (mw * MTW + mt) * 16 + quad * 4 + r;
                float v = acc[mt][nt][r];
                yp[base + ((size_t)co << (3 * LOGDO))] = v;
                if constexpr (STATS) {
                    float yv = (v + bco[mt][r]) * mv;
                    yv = yv >= 0.f ? yv : 0.01f * yv;
                    sacc[mt][r] += yv; s2acc[mt][r] += yv * yv;
                }
            }
        }
    }

    if constexpr (STATS) {
#pragma unroll
        for (int mt = 0; mt < MTW; mt++)
#pragma unroll
            for (int r = 0; r < 4; r++) {
                float s = sacc[mt][r], s2 = s2acc[mt][r];
#pragma unroll
                for (int o = 8; o; o >>= 1) {
                    s  += __shfl_xor(s, o, 16);
                    s2 += __shfl_xor(s2, o, 16);
                }
                if (lr == 0) {
                    int co = (mw * MTW + mt) * 16 + quad * 4 + r;
                    atomicAdd(&st[co * 3 + 0], s);
                    atomicAdd(&st[co * 3 + 1], s2);
                }
            }
        float ms = mvs;
#pragma unroll
        for (int o = 8; o; o >>= 1) ms += __shfl_xor(ms, o, 16);
        if (lr == 0) {
#pragma unroll
            for (int mt = 0; mt < MTW; mt++)
#pragma unroll
                for (int r = 0; r < 4; r++)
                    atomicAdd(&st[((mw * MTW + mt) * 16 + quad * 4 + r) * 3 + 2], ms);
        }
        __syncthreads();
        // bucketed global accumulation: chain length = gridBlocks/64 per address
        int bucket = bx & 63;
        for (int i = tid; i < COUT * 3; i += 256)
            atomicAdd(&part[bucket * COUT * 3 + i], st[i]);
    }
}

__global__ __launch_bounds__(256)
void conv2_kernel() { mfma_gemm_body<0, 64, 64, 32, 64, 5, 4, 4, 64>(g_y1b, g_wb2, g_p2); }
__global__ __launch_bounds__(256)
void conv3_kernel() { mfma_gemm_body<0, 128, 64, 64, 128, 4, 3, 32, 64>(g_y2b, g_wb3, g_p3); }
__global__ __launch_bounds__(256)
void conv4_kernel() { mfma_gemm_body<1, 128, 64, 128, 128, 3, 4, 4, 64>(g_y3b, g_wb4, g_p4); }
__global__ __launch_bounds__(256)
void conv5_kernel(const float* __restrict__ b5) {
    // SPLITK=1 direct store + fused BN stats (replaces post5), bucketed atomics
    mfma_gemm_body<1, 64, 128, 128, 64, 4, 5, 1, 64, true>(g_t1b, g_wb5, g_t2,
                                                           b5, g_mt2, g_part5);
}

// ---------------------------------------------------------------------------
// conv1: bf16 MFMA, LDS-staged A (round-5 verified), fused BN stats
// (bucketed atomics x128, replaces stats1)
// ---------------------------------------------------------------------------
__global__ __launch_bounds__(256)
void conv1_kernel(const float* __restrict__ bias) {
    constexpr int LDA = 40;
    __shared__ __align__(16) ushort As[32 * LDA];
    __shared__ __align__(16) ushort Bs[64 * LDA];
    __shared__ float st[96];
    const int tid = threadIdx.x, bx = blockIdx.x;
    const int wv = tid >> 6, lane = tid & 63;
    const int lr = lane & 15, quad = lane >> 4;

    if (tid < 96) st[tid] = 0.f;

    const int nB = tid >> 2, octB = tid & 3;
    const int vgB = bx * 64 + nB;
    const int bB = vgB >> 15, vB = vgB & 32767;
    const int odB = vB >> 10, ohB = (vB >> 5) & 31, owB = vB & 31;

    auto gatherA = [&](int kt, ushort8& pa) {
        if (tid < 128) {
            int m = tid >> 2, oct = tid & 3;
            pa = *(const ushort8*)&g_wb1[m * 256 + kt + oct * 8];
        }
    };
    auto gatherB = [&](int kt, ushort8& pb) {
        int kg0 = kt + octB * 8;
        int t0 = kg0 >> 2;
        int kd = t0 >> 4, kh = (t0 >> 2) & 3, kw0 = t0 & 3;
        int id = 2 * odB - 1 + kd;
        int ih = 2 * ohB - 1 + kh;
        int iw0 = 2 * owB - 1 + kw0;
        ushort8 v = (ushort8){0, 0, 0, 0, 0, 0, 0, 0};
        if ((unsigned)id < 64u && (unsigned)ih < 64u) {
            const ushort* base = g_x0b + ((((size_t)bB << 18) + (id << 12) + (ih << 6)) << 2);
            if (iw0 >= 0 && iw0 + 1 < 64) {
                v = *(const ushort8*)&base[iw0 << 2];
            } else {
                if ((unsigned)iw0 < 64u) {
                    ushortx4 h = *(const ushortx4*)&base[iw0 << 2];
                    v[0] = h[0]; v[1] = h[1]; v[2] = h[2]; v[3] = h[3];
                }
                if ((unsigned)(iw0 + 1) < 64u) {
                    ushortx4 h = *(const ushortx4*)&base[(iw0 + 1) << 2];
                    v[4] = h[0]; v[5] = h[1]; v[6] = h[2]; v[7] = h[3];
                }
            }
        }
        pb = v;
    };

    accv acc[2];
    acc[0] = (accv){0.f, 0.f, 0.f, 0.f};
    acc[1] = (accv){0.f, 0.f, 0.f, 0.f};
    ushort8 pa, pb, qa, qb;
    gatherA(0, pa); gatherB(0, pb);

    for (int kt = 0; kt < 256; kt += 32) {
        __syncthreads();
        if (tid < 128) { int m = tid >> 2, oct = tid & 3; *(ushort8*)&As[m * LDA + oct * 8] = pa; }
        *(ushort8*)&Bs[nB * LDA + octB * 8] = pb;
        __syncthreads();
        bool more = kt < 224;
        if (more) { gatherA(kt + 32, qa); gatherB(kt + 32, qb); }

        short8 b8 = *(const short8*)&Bs[(wv * 16 + lr) * LDA + quad * 8];
#pragma unroll
        for (int mt = 0; mt < 2; mt++) {
            short8 a8 = *(const short8*)&As[(mt * 16 + lr) * LDA + quad * 8];
            acc[mt] = __builtin_amdgcn_mfma_f32_16x16x32_bf16(a8, b8, acc[mt], 0, 0, 0);
        }
        if (more) { pa = qa; pb = qb; }
    }

    // epilogue: bias+mask+leaky, store y1, fused stats (replaces stats1)
    int vg = bx * 64 + wv * 16 + lr;
    int b = vg >> 15, off = vg & 32767;
    float mv = g_m1[((size_t)b << 15) + off];
    float sacc[2][4], s2acc[2][4];
#pragma unroll
    for (int mt = 0; mt < 2; mt++) {
#pragma unroll
        for (int r = 0; r < 4; r++) {
            int co = mt * 16 + quad * 4 + r;
            float yv = (acc[mt][r] + bias[co]) * mv;
            yv = yv >= 0.f ? yv : 0.01f * yv;
            g_y1[(((size_t)(b * 32 + co)) << 15) + off] = yv;
            sacc[mt][r] = yv; s2acc[mt][r] = yv * yv;
        }
    }
#pragma unroll
    for (int mt = 0; mt < 2; mt++) {
#pragma unroll
        for (int r = 0; r < 4; r++) {
            float s = sacc[mt][r], s2 = s2acc[mt][r];
#pragma unroll
            for (int o = 8; o; o >>= 1) {
                s  += __shfl_xor(s, o, 16);
                s2 += __shfl_xor(s2, o, 16);
            }
            if (lr == 0) {
                int co = mt * 16 + quad * 4 + r;
                atomicAdd(&st[co * 3 + 0], s);
                atomicAdd(&st[co * 3 + 1], s2);
            }
        }
    }
    float ms = mv;
#pragma unroll
    for (int o = 8; o; o >>= 1) ms += __shfl_xor(ms, o, 16);
    if (lr == 0) {
#pragma unroll
        for (int mt = 0; mt < 2; mt++)
#pragma unroll
            for (int r = 0; r < 4; r++)
                atomicAdd(&st[(mt * 16 + quad * 4 + r) * 3 + 2], ms);
    }
    __syncthreads();
    // bucketed global accumulation: chain length = 1024/128 = 8 per address
    if (tid < 96) atomicAdd(&g_part1[(bx & 127) * 96 + tid], st[tid]);
}

// ---------------------------------------------------------------------------
// final: fp32 1x1x1, fully fused load: bias5+mask+leaky+BN. grid 1024.
// BN scales derived by summing g_part5 buckets.
// ---------------------------------------------------------------------------
__global__ __launch_bounds__(256)
void final_kernel(const float* __restrict__ fb, const float* __restrict__ b5,
                  const float* __restrict__ tg2, const float* __restrict__ tbe2,
                  float* __restrict__ out) {
    __shared__ float As[1024];
    __shared__ float Bs[2048];
    __shared__ float sc5[64], sh5[64], bb5[64];
    const int tid = threadIdx.x, tc = tid & 15, tv = tid >> 4;
    const int bx = blockIdx.x;

    if (tid < 64) {
        float s0 = 0.f, s1 = 0.f, cnt = 0.f;
#pragma unroll 4
        for (int bkt = 0; bkt < 64; bkt++) {
            const float* p = g_part5 + bkt * 192 + tid * 3;
            s0 += p[0]; s1 += p[1]; cnt += p[2];
        }
        float n = fmaxf(cnt, 1.f);
        float mean = s0 / n;
        float var = fmaxf(s1 / n - mean * mean, 0.f);
        float rstd = rsqrtf(var + 1e-5f);
        float s = tg2[tid] * rstd;
        sc5[tid] = s; sh5[tid] = tbe2[tid] - mean * s; bb5[tid] = b5[tid];
    }

    float acc[2][4] = {{0.f}};
    for (int kt = 0; kt < 64; kt += 32) {
        __syncthreads();
#pragma unroll
        for (int e = 0; e < 4; e++) As[e * 256 + tid] = g_fwt[kt * 32 + e * 256 + tid];
#pragma unroll
        for (int e = 0; e < 8; e++) {
            int j = e * 256 + tid;
            int kk = j >> 6, n = j & 63;
            int kg = kt + kk;
            int vg = bx * 64 + n;
            int b = vg >> 15, v = vg & 32767;
            float raw = g_t2[(((size_t)(b * 64 + kg)) << 15) + v];
            float mv = g_mt2[((size_t)b << 15) + v];
            float t = (raw + bb5[kg]) * mv;
            t = t >= 0.f ? t : 0.01f * t;
            Bs[kk * 64 + n] = (t * sc5[kg] + sh5[kg]) * mv;
        }
        __syncthreads();
#pragma unroll
        for (int kk = 0; kk < 32; kk++) {
            float2 a2 = *(const float2*)&As[kk * 32 + tc * 2];
            float4 b4 = *(const float4*)&Bs[kk * 64 + tv * 4];
            float a[2] = {a2.x, a2.y};
            float bb[4] = {b4.x, b4.y, b4.z, b4.w};
#pragma unroll
            for (int r = 0; r < 2; r++)
#pragma unroll
                for (int c = 0; c < 4; c++) acc[r][c] = fmaf(a[r], bb[c], acc[r][c]);
        }
    }
#pragma unroll
    for (int r = 0; r < 2; r++) {
        int co = tc * 2 + r;
        float bv = fb[co];
#pragma unroll
        for (int c = 0; c < 4; c++) {
            int vg = bx * 64 + tv * 4 + c;
            int b = vg >> 15, v = vg & 32767;
            out[(((size_t)(b * 32 + co)) << 15) + v] = acc[r][c] + bv;
        }
    }
}

// ---------------------------------------------------------------------------
DEV void red3_and_atomic(float s, float s2, float sm, float* sred, int co) {
#pragma unroll
    for (int off = 32; off; off >>= 1) {
        s  += __shfl_down(s, off, 64);
        s2 += __shfl_down(s2, off, 64);
        sm += __shfl_down(sm, off, 64);
    }
    __shared__ float red[12];
    int lane = threadIdx.x & 63, wvi = threadIdx.x >> 6;
    if (!lane) { red[wvi] = s; red[4 + wvi] = s2; red[8 + wvi] = sm; }
    __syncthreads();
    if (!threadIdx.x) {
        atomicAdd(&sred[co * 32 + 0], red[0] + red[1] + red[2] + red[3]);
        atomicAdd(&sred[co * 32 + 1], red[4] + red[5] + red[6] + red[7]);
        atomicAdd(&sred[co * 32 + 2], red[8] + red[9] + red[10] + red[11]);
    }
}

// ---------------------------------------------------------------------------
// post: sum SPLITK partials + bias + mask + LeakyReLU + stats
// ---------------------------------------------------------------------------
template<int COUT, int LOGDO, int SPLITK, int ITERS, bool WRITE>
DEV void post_body(const float* __restrict__ bias, const float* __restrict__ m2,
                   const float* p, float* y, float* sred) {
    constexpr int Dvox = 1 << (3 * LOGDO);
    constexpr size_t STR = (size_t)2 * COUT * Dvox;
    constexpr int LOGC = (COUT == 128) ? 7 : ((COUT == 64) ? 6 : 5);
    int base = blockIdx.x * (ITERS * 256);
    int co = (base >> (3 * LOGDO)) & (COUT - 1);
    float s = 0.f, s2 = 0.f, sm = 0.f;
#pragma unroll
    for (int it = 0; it < ITERS; it++) {
        int idx = base + it * 256 + threadIdx.x;
        int v = idx & (Dvox - 1);
        int b = idx >> (3 * LOGDO + LOGC);
        float sum = 0.f;
#pragma unroll
        for (int k = 0; k < SPLITK; k++) sum += p[k * STR + idx];
        float mv = m2[((size_t)b << (3 * LOGDO)) + v];
        float yv = (sum + bias[co]) * mv;
        yv = yv >= 0.f ? yv : 0.01f * yv;
        if constexpr (WRITE) y[idx] = yv;
        s += yv; s2 += yv * yv; sm += mv;
    }
    red3_and_atomic(s, s2, sm, sred, co);
}

__global__ __launch_bounds__(256) void post2_kernel(const float* b) { post_body<64, 4, 4, 1, true>(b, g_m2, g_p2, g_y2, g_sred + 4096); }
__global__ __launch_bounds__(256) void post3_kernel(const float* b) { post_body<128, 3, 32, 1, true>(b, g_m3, g_p3, g_y3, g_sred + 8192); }
__global__ __launch_bounds__(256) void post4_kernel(const float* b) { post_body<128, 4, 4, 2, true>(b, g_mt1, g_p4, g_t1, g_sred + 12288); }

// ---------------------------------------------------------------------------
// bn fused with finalize, explicit block index.
// PART>0: derive scales by summing PART stat buckets [bkt][C*3] (conv1 path).
// PART==0: classic g_sred layout [co*32 + s].
// ---------------------------------------------------------------------------
template<int LOGC, int LOGD, int PART>
DEV void bn_fused_body(const float* __restrict__ y, ushort* __restrict__ out,
                       const float* __restrict__ sred, const float* __restrict__ gm,
                       const float* __restrict__ be, const float* __restrict__ m2,
                       int blk) {
    constexpr int C = 1 << LOGC, Dvox = 1 << LOGD;
    __shared__ float sc[C], sh[C];
    int tid = threadIdx.x;
    if (tid < C) {
        float s0, s1, cnt;
        if constexpr (PART > 0) {
            s0 = 0.f; s1 = 0.f; cnt = 0.f;
#pragma unroll 4
            for (int bkt = 0; bkt < PART; bkt++) {
                const float* p = sred + bkt * C * 3 + tid * 3;
                s0 += p[0]; s1 += p[1]; cnt += p[2];
            }
        } else {
            s0 = sred[tid * 32]; s1 = sred[tid * 32 + 1]; cnt = sred[tid * 32 + 2];
        }
        float n = fmaxf(cnt, 1.f);
        float mean = s0 / n;
        float var = fmaxf(s1 / n - mean * mean, 0.f);
        float rstd = rsqrtf(var + 1e-5f);
        float s = gm[tid] * rstd;
        sc[tid] = s; sh[tid] = be[tid] - mean * s;
    }
    __syncthreads();
    int gv = blk * 256 + tid;
    int b = gv >> LOGD, vox = gv & (Dvox - 1);
    float mv = m2[gv];
    const float* yp = y + (((size_t)b << LOGC) << LOGD) + vox;
    ushort* op = out + (size_t)gv * C;
#pragma unroll
    for (int c0 = 0; c0 < C; c0 += 8) {
        ushort pk[8];
#pragma unroll
        for (int j = 0; j < 8; j++) {
            int c = c0 + j;
            float val = yp[(size_t)c << LOGD];
            pk[j] = f2bf((val * sc[c] + sh[c]) * mv);
        }
        *(ushort8*)&op[c0] = (ushort8){pk[0], pk[1], pk[2], pk[3], pk[4], pk[5], pk[6], pk[7]};
    }
}

// bn kernels with fused next-mask blocks
__global__ __launch_bounds__(256)
void bn1_kernel(const float* g, const float* be) {          // grid 288
    if (blockIdx.x < 256) bn_fused_body<5, 15, 128>(g_y1, g_y1b, g_part1, g, be, g_m1, blockIdx.x);
    else mask_down_blk(g_m1, g_m2, 5, 4, blockIdx.x - 256); // mask2: 32 blocks
}
__global__ __launch_bounds__(256)
void bn2_kernel(const float* g, const float* be) {          // grid 36
    if (blockIdx.x < 32) bn_fused_body<6, 12, 0>(g_y2, g_y2b, g_sred + 4096, g, be, g_m2, blockIdx.x);
    else mask_down_blk(g_m2, g_m3, 4, 3, blockIdx.x - 32);  // mask3: 4 blocks
}
__global__ __launch_bounds__(256)
void bn3_kernel(const float* g, const float* be) {          // grid 36
    if (blockIdx.x < 4) bn_fused_body<7, 9, 0>(g_y3, g_y3b, g_sred + 8192, g, be, g_m3, blockIdx.x);
    else mask_up_blk(g_m3, g_mt1, 3, 4, blockIdx.x - 4);    // mask4: 32 blocks
}
__global__ __launch_bounds__(256)
void bn4_kernel(const float* g, const float* be) {          // grid 288
    if (blockIdx.x < 32) bn_fused_body<7, 12, 0>(g_t1, g_t1b, g_sred + 12288, g, be, g_mt1, blockIdx.x);
    else mask_up_blk(g_mt1, g_mt2, 4, 5, blockIdx.x - 32);  // mask5: 256 blocks
}

// ---------------------------------------------------------------------------

extern "C" void kernel_launch(void* const* d_in, const int* in_sizes, int n_in,
                              void* d_out, int out_size, void* d_ws, size_t ws_size,
                              hipStream_t stream) {
    (void)in_sizes; (void)n_in; (void)out_size; (void)d_ws; (void)ws_size;
    const float* feat = (const float*)d_in[0];
    const float* mask = (const float*)d_in[1];
    const float* w1  = (const float*)d_in[2];
    const float* b1  = (const float*)d_in[3];
    const float* g1  = (const float*)d_in[4];
    const float* be1 = (const float*)d_in[5];
    const float* w2  = (const float*)d_in[6];
    const float* b2  = (const float*)d_in[7];
    const float* g2  = (const float*)d_in[8];
    const float* be2 = (const float*)d_in[9];
    const float* w3  = (const float*)d_in[10];
    const float* b3  = (const float*)d_in[11];
    const float* g3  = (const float*)d_in[12];
    const float* be3 = (const float*)d_in[13];
    const float* tw1 = (const float*)d_in[14];
    const float* tb1 = (const float*)d_in[15];
    const float* tg1 = (const float*)d_in[16];
    const float* tbe1= (const float*)d_in[17];
    const float* tw2 = (const float*)d_in[18];
    const float* tb2 = (const float*)d_in[19];
    const float* tg2 = (const float*)d_in[20];
    const float* tbe2= (const float*)d_in[21];
    const float* fw  = (const float*)d_in[22];
    const float* fb  = (const float*)d_in[23];

    prep_all_kernel<<<11104, 256, 0, stream>>>(w1, fw, w2, w3, tw1, tw2, feat, mask);

    // block 1 (bf16 MFMA + fused stats): 4->32, 64^3 -> 32^3
    conv1_kernel<<<1024, 256, 0, stream>>>(b1);
    bn1_kernel<<<288, 256, 0, stream>>>(g1, be1);          // + mask2

    // block 2 (MFMA dbuf): 32->64, 32^3 -> 16^3, K=2048 split 4, NT=64, KT=64
    conv2_kernel<<<dim3(128, 1, 4), 256, 0, stream>>>();
    post2_kernel<<<2048, 256, 0, stream>>>(b2);
    bn2_kernel<<<36, 256, 0, stream>>>(g2, be2);           // + mask3

    // block 3 (MFMA dbuf): 64->128, 16^3 -> 8^3, K=4096 split 32, KT=64
    conv3_kernel<<<dim3(16, 1, 32), 256, 0, stream>>>();
    post3_kernel<<<512, 256, 0, stream>>>(b3);
    bn3_kernel<<<36, 256, 0, stream>>>(g3, be3);           // + mask4

    // up block 1 (MFMA dbuf): 128->128, 8^3 -> 16^3, parity 8 x split 4, NT=64, KT=64
    conv4_kernel<<<dim3(16, 1, 32), 256, 0, stream>>>();
    post4_kernel<<<2048, 256, 0, stream>>>(tb1);
    bn4_kernel<<<288, 256, 0, stream>>>(tg1, tbe1);        // + mask5

    // up block 2 (MFMA dbuf): 128->64, 16^3 -> 32^3, parity 8, KT=64, direct store + fused stats
    conv5_kernel<<<dim3(64, 1, 8), 256, 0, stream>>>(tb2);

    // final dense 1x1x1 conv 64->32 @ 32^3 (bias5+mask+leaky+BN fused on load)
    final_kernel<<<1024, 256, 0, stream>>>(fb, tb2, tg2, tbe2, (float*)d_out);
}

// Round 8
// 256.689 us; speedup vs baseline: 1.0624x; 1.0304x over previous
//
#include <hip/hip_runtime.h>
#include <hip/hip_bf16.h>

#define DEV static __device__ __forceinline__

typedef unsigned short ushort;
typedef __attribute__((ext_vector_type(8))) short short8;
typedef __attribute__((ext_vector_type(8))) ushort ushort8;
typedef __attribute__((ext_vector_type(4))) ushort ushortx4;
typedef __attribute__((ext_vector_type(4))) float accv;

DEV ushort f2bf(float f) {
    __hip_bfloat16 h = __float2bfloat16(f);   // RNE
    return reinterpret_cast<ushort&>(h);
}

DEV float bf2f(ushort u) { return __uint_as_float((unsigned)u << 16); }

// ---------------------------------------------------------------------------
// Static device workspace
// ---------------------------------------------------------------------------
__device__ float    g_sred[5 * 128 * 32];             // [l][co][32]: 0=sum 1=sumsq 2=maskcnt
__device__ float    g_part1[128 * 96];                // conv1 bucketed stats [bkt][co*3+s]
__device__ float    g_part5[64 * 192];                // conv5 bucketed stats [bkt][co*3+s]
__device__ __align__(16) ushort g_y1h[2097152];       // conv1 yv bf16 NCV (pre-BN)
__device__ __align__(16) ushort g_y1b[2097152];       // (2,32^3,32) bf16 VC
__device__ float    g_m1[65536];
__device__ float    g_y2[524288];
__device__ __align__(16) ushort g_y2b[524288];        // (2,16^3,64) bf16 VC
__device__ float    g_m2[8192];
__device__ float    g_y3[131072];
__device__ __align__(16) ushort g_y3b[131072];        // (2,8^3,128) bf16 VC
__device__ float    g_m3[1024];
__device__ float    g_t1[1048576];
__device__ __align__(16) ushort g_t1b[1048576];       // (2,16^3,128) bf16 VC
__device__ float    g_mt1[8192];
__device__ float    g_mt2[65536];
__device__ __align__(16) ushort g_t2b[4194304];       // conv5 yv bf16 NCV (pre-BN)
__device__ __align__(16) ushort g_x0b[2097152];       // (2,64^3,4) bf16 VC masked feat
// split-K partial buffers
__device__ float    g_p2[4194304];                    // 4  x 524288 used
__device__ float    g_p3[4194304];                    // 16 x 131072 used
__device__ float    g_p4[8388608];                    // 4  x 1048576 used
// K-major weights
__device__ __align__(16) ushort g_wb1[8192];          // [32co][256k] bf16, k=tap*4+ci
__device__ __align__(16) ushort g_wb2[131072];
__device__ __align__(16) ushort g_wb3[524288];
__device__ __align__(16) ushort g_wb4[1048576];
__device__ __align__(16) ushort g_wb5[524288];
__device__ float    g_fwt[2048];                      // [k=64][co=32] fp32

// ---------------------------------------------------------------------------
// prep_all (verified round-11/12)
// ---------------------------------------------------------------------------
__global__ __launch_bounds__(256)
void prep_all_kernel(const float* __restrict__ w1, const float* __restrict__ fw,
                     const float* __restrict__ w2, const float* __restrict__ w3,
                     const float* __restrict__ tw1, const float* __restrict__ tw2,
                     const float* __restrict__ feat, const float* __restrict__ mask) {
    int blk = blockIdx.x, tid = threadIdx.x;
    if (blk < 96) {
        int idx = blk * 256 + tid;
        if (idx < 20480) g_sred[idx] = 0.f;
        if (idx < 12288) g_part1[idx] = 0.f;
        if (idx < 12288) g_part5[idx] = 0.f;
        if (idx < 8192) {
            int co = idx >> 8, r = idx & 255;
            int tap = r >> 2, ci = r & 3;
            g_wb1[idx] = f2bf(w1[co * 256 + ci * 64 + tap]);
        }
        if (idx < 2048) { int co = idx >> 6, kg = idx & 63; g_fwt[kg * 32 + co] = fw[idx]; }
    } else if (blk < 608) {
        int idx = (blk - 96) * 256 + tid;
        int co = idx / 2048, r = idx % 2048;
        int ci = r >> 6, tap = r & 63;
        g_wb2[(size_t)co * 2048 + tap * 32 + ci] = f2bf(w2[idx]);
    } else if (blk < 2656) {
        int idx = (blk - 608) * 256 + tid;
        int co = idx / 4096, r = idx % 4096;
        int ci = r >> 6, tap = r & 63;
        g_wb3[(size_t)co * 4096 + tap * 64 + ci] = f2bf(w3[idx]);
    } else if (blk < 6752) {
        int idx = (blk - 2656) * 256 + tid;
        int co = idx / 8192, r = idx % 8192;
        int ci = r >> 6, t64 = r & 63;
        int kd = t64 >> 4, kh = (t64 >> 2) & 3, kw = t64 & 3;
        int pd = (3 - kd) & 1, td = (3 - kd) >> 1;
        int ph = (3 - kh) & 1, th = (3 - kh) >> 1;
        int pw = (3 - kw) & 1, tw = (3 - kw) >> 1;
        int parity = pd * 4 + ph * 2 + pw, t = td * 4 + th * 2 + tw;
        g_wb4[(((size_t)parity * 128 + co) * 8 + t) * 128 + ci] = f2bf(tw1[idx]);
    } else if (blk < 8800) {
        int idx = (blk - 6752) * 256 + tid;
        int co = idx / 8192, r = idx % 8192;
        int ci = r >> 6, t64 = r & 63;
        int kd = t64 >> 4, kh = (t64 >> 2) & 3, kw = t64 & 3;
        int pd = (3 - kd) & 1, td = (3 - kd) >> 1;
        int ph = (3 - kh) & 1, th = (3 - kh) >> 1;
        int pw = (3 - kw) & 1, tw = (3 - kw) >> 1;
        int parity = pd * 4 + ph * 2 + pw, t = td * 4 + th * 2 + tw;
        g_wb5[(((size_t)parity * 64 + co) * 8 + t) * 128 + ci] = f2bf(tw2[idx]);
    } else if (blk < 10848) {
        int idx = (blk - 8800) * 256 + tid;
        int b = idx >> 18, v = idx & 0x3FFFF;
        float mv = mask[idx] > 0.5f ? 1.f : 0.f;
        ushort pk[4];
#pragma unroll
        for (int c = 0; c < 4; c++) pk[c] = f2bf(feat[((b * 4 + c) << 18) + v] * mv);
        *(ushortx4*)&g_x0b[(size_t)idx * 4] = (ushortx4){pk[0], pk[1], pk[2], pk[3]};
    } else {
        int idx = (blk - 10848) * 256 + tid;            // mask1: 65536
        int b = idx >> 15, v = idx & 0x7FFF;
        int od = v >> 10, rem = v & 1023;
        int oh = rem >> 5, ow = rem & 31;
        const float* mp = mask + ((size_t)b << 18);
        float acc = 0.f;
        for (int kd = 0; kd < 4; kd++) {
            int id = 2 * od - 1 + kd;
            if ((unsigned)id >= 64u) continue;
            for (int kh = 0; kh < 4; kh++) {
                int ih = 2 * oh - 1 + kh;
                if ((unsigned)ih >= 64u) continue;
                const float* row = mp + ((size_t)id * 64 + ih) * 64;
                for (int kw = 0; kw < 4; kw++) {
                    int iw = 2 * ow - 1 + kw;
                    if ((unsigned)iw < 64u && row[iw] > 0.5f) acc += 1.f;
                }
            }
        }
        g_m1[idx] = acc > 0.f ? 1.f : 0.f;
    }
}

// ---------------------------------------------------------------------------
// mask dilation bodies with explicit block index (fused into bn kernels)
// ---------------------------------------------------------------------------
DEV void mask_down_blk(const float* mprev, float* mout, int logDin, int logDo, int blk) {
    int Din = 1 << logDin, Do = 1 << logDo;
    int idx = blk * 256 + threadIdx.x;
    int b = idx >> (3 * logDo), v = idx & ((1 << (3 * logDo)) - 1);
    int od = v >> (2 * logDo), rem = v & ((1 << (2 * logDo)) - 1);
    int oh = rem >> logDo, ow = rem & (Do - 1);
    const float* mp = mprev + ((size_t)b << (3 * logDin));
    float acc = 0.f;
    for (int kd = 0; kd < 4; kd++) {
        int id = 2 * od - 1 + kd;
        if ((unsigned)id >= (unsigned)Din) continue;
        for (int kh = 0; kh < 4; kh++) {
            int ih = 2 * oh - 1 + kh;
            if ((unsigned)ih >= (unsigned)Din) continue;
            const float* row = mp + ((size_t)id * Din + ih) * Din;
            for (int kw = 0; kw < 4; kw++) {
                int iw = 2 * ow - 1 + kw;
                if ((unsigned)iw < (unsigned)Din) acc += row[iw];
            }
        }
    }
    mout[idx] = acc > 0.f ? 1.f : 0.f;
}

DEV void mask_up_blk(const float* mprev, float* mout, int logDin, int logDo, int blk) {
    int Din = 1 << logDin, Do = 1 << logDo;
    int idx = blk * 256 + threadIdx.x;
    int b = idx >> (3 * logDo), v = idx & ((1 << (3 * logDo)) - 1);
    int od = v >> (2 * logDo), rem = v & ((1 << (2 * logDo)) - 1);
    int oh = rem >> logDo, ow = rem & (Do - 1);
    const float* mp = mprev + ((size_t)b << (3 * logDin));
    float acc = 0.f;
    for (int kd = 0; kd < 4; kd++) {
        int u = od + kd - 2; if (u < 0 || (u & 1)) continue;
        int id = u >> 1; if (id >= Din) continue;
        for (int kh = 0; kh < 4; kh++) {
            int uh = oh + kh - 2; if (uh < 0 || (uh & 1)) continue;
            int ih = uh >> 1; if (ih >= Din) continue;
            const float* row = mp + ((size_t)id * Din + ih) * Din;
            for (int kw = 0; kw < 4; kw++) {
                int uw = ow + kw - 2; if (uw < 0 || (uw & 1)) continue;
                int iw = uw >> 1; if (iw >= Din) continue;
                acc += row[iw];
            }
        }
    }
    mout[idx] = acc > 0.f ? 1.f : 0.f;
}

// ---------------------------------------------------------------------------
// bf16 MFMA implicit-GEMM, DOUBLE-BUFFERED LDS: one barrier per K-iteration.
// WAR-safe: stage(cur^1) writes a buffer whose last readers were separated
// by the barrier at the end of the previous iteration.
// Per-slot tap decode in gatherB makes KT=64 legal for any CIN >= 8.
// STATS: fused BN-stats epilogue (bucketed global atomics).
// OUTBF: store bf16(yv) (post-bias/mask/leaky) instead of raw fp32.
// ---------------------------------------------------------------------------
template<int MODE, int MT, int NT, int CIN, int COUT, int LOGDI, int LOGDO, int SPLITK,
         int KT, bool STATS = false, bool OUTBF = false>
DEV void mfma_gemm_body(const ushort* __restrict__ xb, const ushort* __restrict__ wb,
                        float* __restrict__ y,
                        const float* __restrict__ bias = nullptr,
                        const float* __restrict__ m2 = nullptr,
                        float* __restrict__ part = nullptr) {
    constexpr int K  = (MODE == 1) ? CIN * 8 : CIN * 64;
    constexpr int KSEG = K / SPLITK;
    constexpr int OCT = KT / 8;                 // ushort8 loads per row per tile
    constexpr int LOGOCT = (KT == 32) ? 2 : 3;
    constexpr int KKN = KT / 32;                // mfma k-steps per tile
    constexpr int LDA = KT + 8;
    constexpr int MTW = MT / 32, NTW = NT / 32;
    constexpr int AR = MT * OCT / 256, BR = NT * OCT / 256;
    constexpr int LCIN = (CIN == 32) ? 5 : ((CIN == 64) ? 6 : 7);
    constexpr int Din = 1 << LOGDI, Do = 1 << LOGDO;
    constexpr int DvoxI = 1 << (3 * LOGDI), DvoxO = 1 << (3 * LOGDO);

    __shared__ __align__(16) ushort As[2][MT * LDA];
    __shared__ __align__(16) ushort Bs[2][NT * LDA];
    __shared__ float st[STATS ? COUT * 3 : 1];

    const int tid = threadIdx.x;
    const int bx = blockIdx.x;
    int pd = 0, ph = 0, pw = 0, ks = 0;
    const ushort* wp = wb;
    if constexpr (MODE == 1) {
        int z = blockIdx.z;
        pd = (z >> 2) & 1; ph = (z >> 1) & 1; pw = z & 1; ks = z >> 3;
        wp = wb + (size_t)(z & 7) * COUT * CIN * 8;
    } else {
        ks = blockIdx.z;
    }

    const int wv = tid >> 6, lane = tid & 63;
    const int mw = wv & 1, nw = wv >> 1;
    const int lr = lane & 15, quad = lane >> 4;

    if constexpr (STATS) {
        for (int i = tid; i < COUT * 3; i += 256) st[i] = 0.f;
        // visibility covered by the prologue __syncthreads
    }

    // hoisted per-slot B voxel decode
    int rB[BR], dB[BR], hB[BR], wBv[BR];
#pragma unroll
    for (int r = 0; r < BR; r++) {
        int slot = r * 256 + tid;
        int n = slot >> LOGOCT;
        int vg = bx * NT + n;
        if constexpr (MODE == 0) {
            rB[r] = vg >> (3 * LOGDO);
            int vv = vg & (DvoxO - 1);
            dB[r] = 2 * (vv >> (2 * LOGDO)) - 1;
            hB[r] = 2 * ((vv >> LOGDO) & (Do - 1)) - 1;
            wBv[r] = 2 * (vv & (Do - 1)) - 1;
        } else {
            rB[r] = vg >> (3 * LOGDI);
            int vv = vg & (DvoxI - 1);
            dB[r] = (vv >> (2 * LOGDI)) + pd - 1;
            hB[r] = ((vv >> LOGDI) & (Din - 1)) + ph - 1;
            wBv[r] = (vv & (Din - 1)) + pw - 1;
        }
    }

    auto gatherA = [&](int kt, ushort8* pa) {
#pragma unroll
        for (int r = 0; r < AR; r++) {
            int slot = r * 256 + tid;
            int m = slot >> LOGOCT, oct = slot & (OCT - 1);
            pa[r] = *(const ushort8*)&wp[(size_t)m * K + kt + oct * 8];
        }
    };
    // per-slot tap decode: a KT=64 tile may span 2 taps at CIN=32, but each
    // thread's ushort8 (8 k-values) is always within one tap (8 <= CIN).
    auto gatherB = [&](int kt, ushort8* pb) {
#pragma unroll
        for (int r = 0; r < BR; r++) {
            int oct = (r * 256 + tid) & (OCT - 1);
            int kk0 = kt + oct * 8;
            int tap = kk0 >> LCIN;
            int ci0 = kk0 & (CIN - 1);
            int id_d, ih_d, iw_d;
            if constexpr (MODE == 0) { id_d = tap >> 4; ih_d = (tap >> 2) & 3; iw_d = tap & 3; }
            else                     { id_d = (tap >> 2) & 1; ih_d = (tap >> 1) & 1; iw_d = tap & 1; }
            int id = dB[r] + id_d, ih = hB[r] + ih_d, iw = wBv[r] + iw_d;
            ushort8 v = (ushort8){0, 0, 0, 0, 0, 0, 0, 0};
            if ((unsigned)id < (unsigned)Din && (unsigned)ih < (unsigned)Din &&
                (unsigned)iw < (unsigned)Din)
                v = *(const ushort8*)&xb[((size_t)rB[r] * DvoxI +
                                          (id << (2 * LOGDI)) + (ih << LOGDI) + iw) * CIN + ci0];
            pb[r] = v;
        }
    };
    auto stage = [&](int buf, ushort8* a, ushort8* b) {
#pragma unroll
        for (int r = 0; r < AR; r++) {
            int slot = r * 256 + tid;
            int m = slot >> LOGOCT, oct = slot & (OCT - 1);
            *(ushort8*)&As[buf][m * LDA + oct * 8] = a[r];
        }
#pragma unroll
        for (int r = 0; r < BR; r++) {
            int slot = r * 256 + tid;
            int n = slot >> LOGOCT, oct = slot & (OCT - 1);
            *(ushort8*)&Bs[buf][n * LDA + oct * 8] = b[r];
        }
    };

    accv acc[MTW][NTW];
#pragma unroll
    for (int mt = 0; mt < MTW; mt++)
#pragma unroll
        for (int nt = 0; nt < NTW; nt++) acc[mt][nt] = (accv){0.f, 0.f, 0.f, 0.f};

    const int kbeg = ks * KSEG, kend = kbeg + KSEG;
    ushort8 pa[AR], pb[BR], qa[AR], qb[BR];
    gatherA(kbeg, pa);
    gatherB(kbeg, pb);
    stage(0, pa, pb);
    __syncthreads();

    int cur = 0;
    for (int kt = kbeg; kt < kend; kt += KT) {
        bool more = (kt + KT) < kend;
        if (more) { gatherA(kt + KT, qa); gatherB(kt + KT, qb); }

        short8 af[MTW][KKN], bfr[NTW][KKN];
#pragma unroll
        for (int mt = 0; mt < MTW; mt++)
#pragma unroll
            for (int kk = 0; kk < KKN; kk++)
                af[mt][kk] = *(const short8*)&As[cur][((mw * MTW + mt) * 16 + lr) * LDA +
                                                     kk * 32 + quad * 8];
#pragma unroll
        for (int nt = 0; nt < NTW; nt++)
#pragma unroll
            for (int kk = 0; kk < KKN; kk++)
                bfr[nt][kk] = *(const short8*)&Bs[cur][((nw * NTW + nt) * 16 + lr) * LDA +
                                                      kk * 32 + quad * 8];
#pragma unroll
        for (int kk = 0; kk < KKN; kk++)
#pragma unroll
            for (int mt = 0; mt < MTW; mt++)
#pragma unroll
                for (int nt = 0; nt < NTW; nt++)
                    acc[mt][nt] = __builtin_amdgcn_mfma_f32_16x16x32_bf16(
                        af[mt][kk], bfr[nt][kk], acc[mt][nt], 0, 0, 0);
        if (more) {
            stage(cur ^ 1, qa, qb);
            __syncthreads();
            cur ^= 1;
        }
    }

    // ---- epilogue: scatter store (+ optional fused stats) ----
    float* yp = y + (size_t)ks * (2 * COUT * DvoxO);
    float sacc[MTW][4], s2acc[MTW][4], bco[MTW][4];
    float mvs = 0.f;
    if constexpr (STATS) {
#pragma unroll
        for (int mt = 0; mt < MTW; mt++)
#pragma unroll
            for (int r = 0; r < 4; r++) {
                sacc[mt][r] = 0.f; s2acc[mt][r] = 0.f;
                bco[mt][r] = bias[(mw * MTW + mt) * 16 + quad * 4 + r];
            }
    }
#pragma unroll
    for (int nt = 0; nt < NTW; nt++) {
        int vg = bx * NT + (nw * NTW + nt) * 16 + lr;
        int b, vvox;
        if constexpr (MODE == 1) {
            b = vg >> (3 * LOGDI);
            int vv = vg & (DvoxI - 1);
            int odp = vv >> (2 * LOGDI), ohp = (vv >> LOGDI) & (Din - 1), owp = vv & (Din - 1);
            vvox = ((2 * odp + pd) << (2 * LOGDO)) + ((2 * ohp + ph) << LOGDO) + (2 * owp + pw);
        } else {
            b = vg >> (3 * LOGDO);
            vvox = vg & (DvoxO - 1);
        }
        float mv = 0.f;
        if constexpr (STATS) {
            mv = m2[((size_t)b << (3 * LOGDO)) + vvox];
            mvs += mv;
        }
        size_t base = (((size_t)b * COUT) << (3 * LOGDO)) + vvox;
#pragma unroll
        for (int mt = 0; mt < MTW; mt++) {
#pragma unroll
            for (int r = 0; r < 4; r++) {
                int co = (mw * MTW + mt) * 16 + quad * 4 + r;
                float v = acc[mt][nt][r];
                size_t oidx = base + ((size_t)co << (3 * LOGDO));
                if constexpr (STATS) {
                    float yv = (v + bco[mt][r]) * mv;
                    yv = yv >= 0.f ? yv : 0.01f * yv;
                    if constexpr (OUTBF) ((ushort*)yp)[oidx] = f2bf(yv);
                    else                 yp[oidx] = v;
                    sacc[mt][r] += yv; s2acc[mt][r] += yv * yv;
                } else {
                    yp[oidx] = v;
                }
            }
        }
    }

    if constexpr (STATS) {
#pragma unroll
        for (int mt = 0; mt < MTW; mt++)
#pragma unroll
            for (int r = 0; r < 4; r++) {
                float s = sacc[mt][r], s2 = s2acc[mt][r];
#pragma unroll
                for (int o = 8; o; o >>= 1) {
                    s  += __shfl_xor(s, o, 16);
                    s2 += __shfl_xor(s2, o, 16);
                }
                if (lr == 0) {
                    int co = (mw * MTW + mt) * 16 + quad * 4 + r;
                    atomicAdd(&st[co * 3 + 0], s);
                    atomicAdd(&st[co * 3 + 1], s2);
                }
            }
        float ms = mvs;
#pragma unroll
        for (int o = 8; o; o >>= 1) ms += __shfl_xor(ms, o, 16);
        if (lr == 0) {
#pragma unroll
            for (int mt = 0; mt < MTW; mt++)
#pragma unroll
                for (int r = 0; r < 4; r++)
                    atomicAdd(&st[((mw * MTW + mt) * 16 + quad * 4 + r) * 3 + 2], ms);
        }
        __syncthreads();
        // bucketed global accumulation: chain length = gridBlocks/64 per address
        int bucket = bx & 63;
        for (int i = tid; i < COUT * 3; i += 256)
            atomicAdd(&part[bucket * COUT * 3 + i], st[i]);
    }
}

__global__ __launch_bounds__(256)
void conv2_kernel() { mfma_gemm_body<0, 64, 64, 32, 64, 5, 4, 4, 64>(g_y1b, g_wb2, g_p2); }
__global__ __launch_bounds__(256)
void conv3_kernel() { mfma_gemm_body<0, 128, 32, 64, 128, 4, 3, 16, 64>(g_y2b, g_wb3, g_p3); }
__global__ __launch_bounds__(256)
void conv4_kernel() { mfma_gemm_body<1, 128, 64, 128, 128, 3, 4, 4, 64>(g_y3b, g_wb4, g_p4); }
__global__ __launch_bounds__(256)
void conv5_kernel(const float* __restrict__ b5) {
    // SPLITK=1, fused BN stats, stores bf16(yv) (bias+mask+leaky applied)
    mfma_gemm_body<1, 64, 128, 128, 64, 4, 5, 1, 64, true, true>(
        g_t1b, g_wb5, (float*)g_t2b, b5, g_mt2, g_part5);
}

// ---------------------------------------------------------------------------
// conv1: bf16 MFMA, LDS-staged A (round-5 verified), fused BN stats
// (bucketed atomics x128), stores bf16(yv) into g_y1h
// ---------------------------------------------------------------------------
__global__ __launch_bounds__(256)
void conv1_kernel(const float* __restrict__ bias) {
    constexpr int LDA = 40;
    __shared__ __align__(16) ushort As[32 * LDA];
    __shared__ __align__(16) ushort Bs[64 * LDA];
    __shared__ float st[96];
    const int tid = threadIdx.x, bx = blockIdx.x;
    const int wv = tid >> 6, lane = tid & 63;
    const int lr = lane & 15, quad = lane >> 4;

    if (tid < 96) st[tid] = 0.f;

    const int nB = tid >> 2, octB = tid & 3;
    const int vgB = bx * 64 + nB;
    const int bB = vgB >> 15, vB = vgB & 32767;
    const int odB = vB >> 10, ohB = (vB >> 5) & 31, owB = vB & 31;

    auto gatherA = [&](int kt, ushort8& pa) {
        if (tid < 128) {
            int m = tid >> 2, oct = tid & 3;
            pa = *(const ushort8*)&g_wb1[m * 256 + kt + oct * 8];
        }
    };
    auto gatherB = [&](int kt, ushort8& pb) {
        int kg0 = kt + octB * 8;
        int t0 = kg0 >> 2;
        int kd = t0 >> 4, kh = (t0 >> 2) & 3, kw0 = t0 & 3;
        int id = 2 * odB - 1 + kd;
        int ih = 2 * ohB - 1 + kh;
        int iw0 = 2 * owB - 1 + kw0;
        ushort8 v = (ushort8){0, 0, 0, 0, 0, 0, 0, 0};
        if ((unsigned)id < 64u && (unsigned)ih < 64u) {
            const ushort* base = g_x0b + ((((size_t)bB << 18) + (id << 12) + (ih << 6)) << 2);
            if (iw0 >= 0 && iw0 + 1 < 64) {
                v = *(const ushort8*)&base[iw0 << 2];
            } else {
                if ((unsigned)iw0 < 64u) {
                    ushortx4 h = *(const ushortx4*)&base[iw0 << 2];
                    v[0] = h[0]; v[1] = h[1]; v[2] = h[2]; v[3] = h[3];
                }
                if ((unsigned)(iw0 + 1) < 64u) {
                    ushortx4 h = *(const ushortx4*)&base[(iw0 + 1) << 2];
                    v[4] = h[0]; v[5] = h[1]; v[6] = h[2]; v[7] = h[3];
                }
            }
        }
        pb = v;
    };

    accv acc[2];
    acc[0] = (accv){0.f, 0.f, 0.f, 0.f};
    acc[1] = (accv){0.f, 0.f, 0.f, 0.f};
    ushort8 pa, pb, qa, qb;
    gatherA(0, pa); gatherB(0, pb);

    for (int kt = 0; kt < 256; kt += 32) {
        __syncthreads();
        if (tid < 128) { int m = tid >> 2, oct = tid & 3; *(ushort8*)&As[m * LDA + oct * 8] = pa; }
        *(ushort8*)&Bs[nB * LDA + octB * 8] = pb;
        __syncthreads();
        bool more = kt < 224;
        if (more) { gatherA(kt + 32, qa); gatherB(kt + 32, qb); }

        short8 b8 = *(const short8*)&Bs[(wv * 16 + lr) * LDA + quad * 8];
#pragma unroll
        for (int mt = 0; mt < 2; mt++) {
            short8 a8 = *(const short8*)&As[(mt * 16 + lr) * LDA + quad * 8];
            acc[mt] = __builtin_amdgcn_mfma_f32_16x16x32_bf16(a8, b8, acc[mt], 0, 0, 0);
        }
        if (more) { pa = qa; pb = qb; }
    }

    // epilogue: bias+mask+leaky, store bf16 y1, fused stats (replaces stats1)
    int vg = bx * 64 + wv * 16 + lr;
    int b = vg >> 15, off = vg & 32767;
    float mv = g_m1[((size_t)b << 15) + off];
    float sacc[2][4], s2acc[2][4];
#pragma unroll
    for (int mt = 0; mt < 2; mt++) {
#pragma unroll
        for (int r = 0; r < 4; r++) {
            int co = mt * 16 + quad * 4 + r;
            float yv = (acc[mt][r] + bias[co]) * mv;
            yv = yv >= 0.f ? yv : 0.01f * yv;
            g_y1h[(((size_t)(b * 32 + co)) << 15) + off] = f2bf(yv);
            sacc[mt][r] = yv; s2acc[mt][r] = yv * yv;
        }
    }
#pragma unroll
    for (int mt = 0; mt < 2; mt++) {
#pragma unroll
        for (int r = 0; r < 4; r++) {
            float s = sacc[mt][r], s2 = s2acc[mt][r];
#pragma unroll
            for (int o = 8; o; o >>= 1) {
                s  += __shfl_xor(s, o, 16);
                s2 += __shfl_xor(s2, o, 16);
            }
            if (lr == 0) {
                int co = mt * 16 + quad * 4 + r;
                atomicAdd(&st[co * 3 + 0], s);
                atomicAdd(&st[co * 3 + 1], s2);
            }
        }
    }
    float ms = mv;
#pragma unroll
    for (int o = 8; o; o >>= 1) ms += __shfl_xor(ms, o, 16);
    if (lr == 0) {
#pragma unroll
        for (int mt = 0; mt < 2; mt++)
#pragma unroll
            for (int r = 0; r < 4; r++)
                atomicAdd(&st[(mt * 16 + quad * 4 + r) * 3 + 2], ms);
    }
    __syncthreads();
    // bucketed global accumulation: chain length = 1024/128 = 8 per address
    if (tid < 96) atomicAdd(&g_part1[(bx & 127) * 96 + tid], st[tid]);
}

// ---------------------------------------------------------------------------
// final: fp32 1x1x1 on bf16 yv input (bias/mask/leaky already applied by
// conv5); only BN affine on load. grid 1024.
// ---------------------------------------------------------------------------
__global__ __launch_bounds__(256)
void final_kernel(const float* __restrict__ fb,
                  const float* __restrict__ tg2, const float* __restrict__ tbe2,
                  float* __restrict__ out) {
    __shared__ float As[1024];
    __shared__ float Bs[2048];
    __shared__ float sc5[64], sh5[64];
    const int tid = threadIdx.x, tc = tid & 15, tv = tid >> 4;
    const int bx = blockIdx.x;

    if (tid < 64) {
        float s0 = 0.f, s1 = 0.f, cnt = 0.f;
#pragma unroll 4
        for (int bkt = 0; bkt < 64; bkt++) {
            const float* p = g_part5 + bkt * 192 + tid * 3;
            s0 += p[0]; s1 += p[1]; cnt += p[2];
        }
        float n = fmaxf(cnt, 1.f);
        float mean = s0 / n;
        float var = fmaxf(s1 / n - mean * mean, 0.f);
        float rstd = rsqrtf(var + 1e-5f);
        float s = tg2[tid] * rstd;
        sc5[tid] = s; sh5[tid] = tbe2[tid] - mean * s;
    }

    float acc[2][4] = {{0.f}};
    for (int kt = 0; kt < 64; kt += 32) {
        __syncthreads();
#pragma unroll
        for (int e = 0; e < 4; e++) As[e * 256 + tid] = g_fwt[kt * 32 + e * 256 + tid];
#pragma unroll
        for (int e = 0; e < 8; e++) {
            int j = e * 256 + tid;
            int kk = j >> 6, n = j & 63;
            int kg = kt + kk;
            int vg = bx * 64 + n;
            int b = vg >> 15, v = vg & 32767;
            float yv = bf2f(g_t2b[(((size_t)(b * 64 + kg)) << 15) + v]);
            float mv = g_mt2[((size_t)b << 15) + v];
            Bs[kk * 64 + n] = (yv * sc5[kg] + sh5[kg]) * mv;
        }
        __syncthreads();
#pragma unroll
        for (int kk = 0; kk < 32; kk++) {
            float2 a2 = *(const float2*)&As[kk * 32 + tc * 2];
            float4 b4 = *(const float4*)&Bs[kk * 64 + tv * 4];
            float a[2] = {a2.x, a2.y};
            float bb[4] = {b4.x, b4.y, b4.z, b4.w};
#pragma unroll
            for (int r = 0; r < 2; r++)
#pragma unroll
                for (int c = 0; c < 4; c++) acc[r][c] = fmaf(a[r], bb[c], acc[r][c]);
        }
    }
#pragma unroll
    for (int r = 0; r < 2; r++) {
        int co = tc * 2 + r;
        float bv = fb[co];
#pragma unroll
        for (int c = 0; c < 4; c++) {
            int vg = bx * 64 + tv * 4 + c;
            int b = vg >> 15, v = vg & 32767;
            out[(((size_t)(b * 32 + co)) << 15) + v] = acc[r][c] + bv;
        }
    }
}

// ---------------------------------------------------------------------------
DEV void red3_and_atomic(float s, float s2, float sm, float* sred, int co) {
#pragma unroll
    for (int off = 32; off; off >>= 1) {
        s  += __shfl_down(s, off, 64);
        s2 += __shfl_down(s2, off, 64);
        sm += __shfl_down(sm, off, 64);
    }
    __shared__ float red[12];
    int lane = threadIdx.x & 63, wvi = threadIdx.x >> 6;
    if (!lane) { red[wvi] = s; red[4 + wvi] = s2; red[8 + wvi] = sm; }
    __syncthreads();
    if (!threadIdx.x) {
        atomicAdd(&sred[co * 32 + 0], red[0] + red[1] + red[2] + red[3]);
        atomicAdd(&sred[co * 32 + 1], red[4] + red[5] + red[6] + red[7]);
        atomicAdd(&sred[co * 32 + 2], red[8] + red[9] + red[10] + red[11]);
    }
}

// ---------------------------------------------------------------------------
// post: sum SPLITK partials + bias + mask + LeakyReLU + stats
// ---------------------------------------------------------------------------
template<int COUT, int LOGDO, int SPLITK, int ITERS, bool WRITE>
DEV void post_body(const float* __restrict__ bias, const float* __restrict__ m2,
                   const float* p, float* y, float* sred) {
    constexpr int Dvox = 1 << (3 * LOGDO);
    constexpr size_t STR = (size_t)2 * COUT * Dvox;
    constexpr int LOGC = (COUT == 128) ? 7 : ((COUT == 64) ? 6 : 5);
    int base = blockIdx.x * (ITERS * 256);
    int co = (base >> (3 * LOGDO)) & (COUT - 1);
    float s = 0.f, s2 = 0.f, sm = 0.f;
#pragma unroll
    for (int it = 0; it < ITERS; it++) {
        int idx = base + it * 256 + threadIdx.x;
        int v = idx & (Dvox - 1);
        int b = idx >> (3 * LOGDO + LOGC);
        float sum = 0.f;
#pragma unroll
        for (int k = 0; k < SPLITK; k++) sum += p[k * STR + idx];
        float mv = m2[((size_t)b << (3 * LOGDO)) + v];
        float yv = (sum + bias[co]) * mv;
        yv = yv >= 0.f ? yv : 0.01f * yv;
        if constexpr (WRITE) y[idx] = yv;
        s += yv; s2 += yv * yv; sm += mv;
    }
    red3_and_atomic(s, s2, sm, sred, co);
}

__global__ __launch_bounds__(256) void post2_kernel(const float* b) { post_body<64, 4, 4, 1, true>(b, g_m2, g_p2, g_y2, g_sred + 4096); }
__global__ __launch_bounds__(256) void post3_kernel(const float* b) { post_body<128, 3, 16, 1, true>(b, g_m3, g_p3, g_y3, g_sred + 8192); }
__global__ __launch_bounds__(256) void post4_kernel(const float* b) { post_body<128, 4, 4, 2, true>(b, g_mt1, g_p4, g_t1, g_sred + 12288); }

// ---------------------------------------------------------------------------
// bn fused with finalize, explicit block index.
// PART>0: derive scales by summing PART stat buckets [bkt][C*3].
// PART==0: classic g_sred layout [co*32 + s].
// YT: float (fp32 input) or ushort (bf16 input).
// ---------------------------------------------------------------------------
template<int LOGC, int LOGD, int PART, typename YT>
DEV void bn_fused_body(const YT* __restrict__ y, ushort* __restrict__ out,
                       const float* __restrict__ sred, const float* __restrict__ gm,
                       const float* __restrict__ be, const float* __restrict__ m2,
                       int blk) {
    constexpr int C = 1 << LOGC, Dvox = 1 << LOGD;
    __shared__ float sc[C], sh[C];
    int tid = threadIdx.x;
    if (tid < C) {
        float s0, s1, cnt;
        if constexpr (PART > 0) {
            s0 = 0.f; s1 = 0.f; cnt = 0.f;
#pragma unroll 4
            for (int bkt = 0; bkt < PART; bkt++) {
                const float* p = sred + bkt * C * 3 + tid * 3;
                s0 += p[0]; s1 += p[1]; cnt += p[2];
            }
        } else {
            s0 = sred[tid * 32]; s1 = sred[tid * 32 + 1]; cnt = sred[tid * 32 + 2];
        }
        float n = fmaxf(cnt, 1.f);
        float mean = s0 / n;
        float var = fmaxf(s1 / n - mean * mean, 0.f);
        float rstd = rsqrtf(var + 1e-5f);
        float s = gm[tid] * rstd;
        sc[tid] = s; sh[tid] = be[tid] - mean * s;
    }
    __syncthreads();
    int gv = blk * 256 + tid;
    int b = gv >> LOGD, vox = gv & (Dvox - 1);
    float mv = m2[gv];
    const YT* yp = y + (((size_t)b << LOGC) << LOGD) + vox;
    ushort* op = out + (size_t)gv * C;
#pragma unroll
    for (int c0 = 0; c0 < C; c0 += 8) {
        ushort pk[8];
#pragma unroll
        for (int j = 0; j < 8; j++) {
            int c = c0 + j;
            float val;
            if constexpr (sizeof(YT) == 2) val = bf2f((ushort)yp[(size_t)c << LOGD]);
            else                           val = yp[(size_t)c << LOGD];
            pk[j] = f2bf((val * sc[c] + sh[c]) * mv);
        }
        *(ushort8*)&op[c0] = (ushort8){pk[0], pk[1], pk[2], pk[3], pk[4], pk[5], pk[6], pk[7]};
    }
}

// bn kernels with fused next-mask blocks
__global__ __launch_bounds__(256)
void bn1_kernel(const float* g, const float* be) {          // grid 288
    if (blockIdx.x < 256) bn_fused_body<5, 15, 128>(g_y1h, g_y1b, g_part1, g, be, g_m1, blockIdx.x);
    else mask_down_blk(g_m1, g_m2, 5, 4, blockIdx.x - 256); // mask2: 32 blocks
}
__global__ __launch_bounds__(256)
void bn2_kernel(const float* g, const float* be) {          // grid 36
    if (blockIdx.x < 32) bn_fused_body<6, 12, 0>(g_y2, g_y2b, g_sred + 4096, g, be, g_m2, blockIdx.x);
    else mask_down_blk(g_m2, g_m3, 4, 3, blockIdx.x - 32);  // mask3: 4 blocks
}
__global__ __launch_bounds__(256)
void bn3_kernel(const float* g, const float* be) {          // grid 36
    if (blockIdx.x < 4) bn_fused_body<7, 9, 0>(g_y3, g_y3b, g_sred + 8192, g, be, g_m3, blockIdx.x);
    else mask_up_blk(g_m3, g_mt1, 3, 4, blockIdx.x - 4);    // mask4: 32 blocks
}
__global__ __launch_bounds__(256)
void bn4_kernel(const float* g, const float* be) {          // grid 288
    if (blockIdx.x < 32) bn_fused_body<7, 12, 0>(g_t1, g_t1b, g_sred + 12288, g, be, g_mt1, blockIdx.x);
    else mask_up_blk(g_mt1, g_mt2, 4, 5, blockIdx.x - 32);  // mask5: 256 blocks
}

// ---------------------------------------------------------------------------

extern "C" void kernel_launch(void* const* d_in, const int* in_sizes, int n_in,
                              void* d_out, int out_size, void* d_ws, size_t ws_size,
                              hipStream_t stream) {
    (void)in_sizes; (void)n_in; (void)out_size; (void)d_ws; (void)ws_size;
    const float* feat = (const float*)d_in[0];
    const float* mask = (const float*)d_in[1];
    const float* w1  = (const float*)d_in[2];
    const float* b1  = (const float*)d_in[3];
    const float* g1  = (const float*)d_in[4];
    const float* be1 = (const float*)d_in[5];
    const float* w2  = (const float*)d_in[6];
    const float* b2  = (const float*)d_in[7];
    const float* g2  = (const float*)d_in[8];
    const float* be2 = (const float*)d_in[9];
    const float* w3  = (const float*)d_in[10];
    const float* b3  = (const float*)d_in[11];
    const float* g3  = (const float*)d_in[12];
    const float* be3 = (const float*)d_in[13];
    const float* tw1 = (const float*)d_in[14];
    const float* tb1 = (const float*)d_in[15];
    const float* tg1 = (const float*)d_in[16];
    const float* tbe1= (const float*)d_in[17];
    const float* tw2 = (const float*)d_in[18];
    const float* tb2 = (const float*)d_in[19];
    const float* tg2 = (const float*)d_in[20];
    const float* tbe2= (const float*)d_in[21];
    const float* fw  = (const float*)d_in[22];
    const float* fb  = (const float*)d_in[23];

    prep_all_kernel<<<11104, 256, 0, stream>>>(w1, fw, w2, w3, tw1, tw2, feat, mask);

    // block 1 (bf16 MFMA + fused stats, bf16 y1): 4->32, 64^3 -> 32^3
    conv1_kernel<<<1024, 256, 0, stream>>>(b1);
    bn1_kernel<<<288, 256, 0, stream>>>(g1, be1);          // + mask2

    // block 2 (MFMA dbuf): 32->64, 32^3 -> 16^3, K=2048 split 4, NT=64, KT=64
    conv2_kernel<<<dim3(128, 1, 4), 256, 0, stream>>>();
    post2_kernel<<<2048, 256, 0, stream>>>(b2);
    bn2_kernel<<<36, 256, 0, stream>>>(g2, be2);           // + mask3

    // block 3 (MFMA dbuf): 64->128, 16^3 -> 8^3, K=4096 split 16, NT=32, KT=64
    conv3_kernel<<<dim3(32, 1, 16), 256, 0, stream>>>();
    post3_kernel<<<512, 256, 0, stream>>>(b3);
    bn3_kernel<<<36, 256, 0, stream>>>(g3, be3);           // + mask4

    // up block 1 (MFMA dbuf): 128->128, 8^3 -> 16^3, parity 8 x split 4, NT=64, KT=64
    conv4_kernel<<<dim3(16, 1, 32), 256, 0, stream>>>();
    post4_kernel<<<2048, 256, 0, stream>>>(tb1);
    bn4_kernel<<<288, 256, 0, stream>>>(tg1, tbe1);        // + mask5

    // up block 2 (MFMA dbuf): 128->64, 16^3 -> 32^3, parity 8, KT=64,
    // stores bf16(yv) + fused stats
    conv5_kernel<<<dim3(64, 1, 8), 256, 0, stream>>>(tb2);

    // final dense 1x1x1 conv 64->32 @ 32^3 (BN affine fused on bf16 load)
    final_kernel<<<1024, 256, 0, stream>>>(fb, tg2, tbe2, (float*)d_out);
}